// Round 3
// baseline (906.603 us; speedup 1.0000x reference)
//
#include <hip/hip_runtime.h>
#include <math.h>

typedef unsigned short u16;
typedef __bf16 bf16x8 __attribute__((ext_vector_type(8)));
typedef float f32x4 __attribute__((ext_vector_type(4)));

#define T_TOK 4096
#define DIM   1024
#define HID   4096
#define NE    8
#define TOPK  3
#define NPAIR 12288   // T_TOK * TOPK

// ---------------- ws layout (bytes) ----------------
// ctrl ints: [0..7]=ecnt, [8..15]=eoff, [16..23]=efill
constexpr size_t OFF_CTRL = 0;
constexpr size_t OFF_XB   = 256;
constexpr size_t OFF_W12T = OFF_XB   + (size_t)T_TOK * DIM * 2;
constexpr size_t OFF_W3T  = OFF_W12T + (size_t)NE * 2 * HID * DIM * 2;
constexpr size_t OFF_HID  = OFF_W3T  + (size_t)NE * DIM * HID * 2;
constexpr size_t OFF_Y    = OFF_HID  + (size_t)NPAIR * HID * 2;
constexpr size_t OFF_PTOK = OFF_Y    + (size_t)NPAIR * DIM * 4;
constexpr size_t OFF_TE   = OFF_PTOK + (size_t)NPAIR * 4;
constexpr size_t OFF_TW   = OFF_TE   + (size_t)T_TOK * TOPK * 4;
constexpr size_t OFF_TS   = OFF_TW   + (size_t)T_TOK * TOPK * 4;

__device__ __forceinline__ u16 f2bf(float f) {
    unsigned u = __builtin_bit_cast(unsigned, f);
    u += 0x7fffu + ((u >> 16) & 1u);   // RNE
    return (u16)(u >> 16);
}

// async global->LDS DMA, 16B per lane; LDS dst = wave-uniform base + lane*16
__device__ __forceinline__ void ld_g2l(const u16* g, u16* l) {
    __builtin_amdgcn_global_load_lds((__attribute__((address_space(1))) unsigned*)(g),
                                     (__attribute__((address_space(3))) unsigned*)(l),
                                     16, 0, 0);
}

// raw sync primitives: raw s_barrier does NOT drain vmcnt (that's the point)
#define VMCNT(N) asm volatile("s_waitcnt vmcnt(" #N ")" ::: "memory")
#define LGKM0  asm volatile("s_waitcnt lgkmcnt(0)" ::: "memory")
#define SBAR   __builtin_amdgcn_s_barrier()
#define SCHED0 __builtin_amdgcn_sched_barrier(0)
#define PRIO1  __builtin_amdgcn_s_setprio(1)
#define PRIO0  __builtin_amdgcn_s_setprio(0)

// quarter staging macros (2 global_load_lds each); half-tile H0 = A02+B01, H1 = B23+A13
#define STAGE_A02(dst) { ld_g2l(srcA[0], (dst) + (0 * 64 + wave * 8) * 64); \
                         ld_g2l(srcA[2], (dst) + (2 * 64 + wave * 8) * 64); }
#define STAGE_B01(dst) { ld_g2l(srcB[0], (dst) + 16384 + (0 * 64 + wave * 8) * 64); \
                         ld_g2l(srcB[1], (dst) + 16384 + (1 * 64 + wave * 8) * 64); }
#define STAGE_B23(dst) { ld_g2l(srcB[2], (dst) + 16384 + (2 * 64 + wave * 8) * 64); \
                         ld_g2l(srcB[3], (dst) + 16384 + (3 * 64 + wave * 8) * 64); }
#define STAGE_A13(dst) { ld_g2l(srcA[1], (dst) + (1 * 64 + wave * 8) * 64); \
                         ld_g2l(srcA[3], (dst) + (3 * 64 + wave * 8) * 64); }
#define ADV()          { _Pragma("unroll") \
                         for (int r_ = 0; r_ < 4; ++r_) { srcA[r_] += 64; srcB[r_] += 64; } }

// ---------------- transpose-cast: [E][K][N] fp32 -> [E][N][K] bf16 ----------------
__global__ __launch_bounds__(256) void transpose_cast_kernel(const float* __restrict__ in,
                                                             u16* __restrict__ out, int K, int N) {
    __shared__ float tile[64][33];
    const float* inp = in + (size_t)blockIdx.z * K * N;
    u16* outp = out + (size_t)blockIdx.z * K * N;
    const int n0 = blockIdx.x * 32, k0 = blockIdx.y * 64;
    const int tid = threadIdx.x;
#pragma unroll
    for (int i = 0; i < 2; ++i) {
        int k = i * 32 + (tid >> 3);
        int c4 = (tid & 7) * 4;
        float4 f = *(const float4*)(inp + (size_t)(k0 + k) * N + n0 + c4);
        tile[k][c4 + 0] = f.x; tile[k][c4 + 1] = f.y;
        tile[k][c4 + 2] = f.z; tile[k][c4 + 3] = f.w;
    }
    __syncthreads();
    const int n = tid >> 3, c = (tid & 7) * 8;
    u16 buf[8];
#pragma unroll
    for (int j = 0; j < 8; ++j) buf[j] = f2bf(tile[c + j][n]);
    *(uint4*)(outp + (size_t)(n0 + n) * K + k0 + c) = *(uint4*)buf;
}

// ---------------- router (fused x->bf16 cast, block-level atomics) ----------------
__global__ __launch_bounds__(256) void router_kernel(const float* __restrict__ x,
                                                     const float* __restrict__ rw,
                                                     const float* __restrict__ rb,
                                                     u16* __restrict__ xb,
                                                     int* __restrict__ tok_expert,
                                                     float* __restrict__ tok_w,
                                                     int* __restrict__ ctrl,
                                                     float* __restrict__ aux) {
    __shared__ int hist[NE];
    __shared__ float auxsh;
    const int tid = threadIdx.x;
    if (tid < NE) hist[tid] = 0;
    if (tid == NE) auxsh = 0.f;
    __syncthreads();

    const int wave = tid >> 6, lane = tid & 63;
    const int t = blockIdx.x * 4 + wave;
    const float* xr = x + (size_t)t * DIM;
    u16* xbr = xb + (size_t)t * DIM;

    float p[NE];
#pragma unroll
    for (int e = 0; e < NE; e++) p[e] = 0.f;
#pragma unroll
    for (int q = 0; q < 4; ++q) {
        const int d = q * 256 + lane * 4;
        float4 f = *(const float4*)(xr + d);
        uint2 v;
        v.x = (unsigned)f2bf(f.x) | ((unsigned)f2bf(f.y) << 16);
        v.y = (unsigned)f2bf(f.z) | ((unsigned)f2bf(f.w) << 16);
        *(uint2*)(xbr + d) = v;
#pragma unroll
        for (int e = 0; e < NE; e++) {
            float4 w = *(const float4*)(rw + e * DIM + d);
            p[e] += f.x * w.x + f.y * w.y + f.z * w.z + f.w * w.w;
        }
    }
#pragma unroll
    for (int e = 0; e < NE; e++) {
#pragma unroll
        for (int off = 32; off; off >>= 1) p[e] += __shfl_down(p[e], off, 64);
    }
    if (lane == 0) {
        float s[NE]; float auxs = 0.f;
#pragma unroll
        for (int e = 0; e < NE; e++) {
            float lg = p[e] + rb[e];
            auxs += lg * lg;
            s[e] = 1.f / (1.f + __expf(-lg));
        }
        atomicAdd(&auxsh, auxs);
        unsigned mask = 0; float wsum = 0.f;
        int idxs[TOPK]; float vals[TOPK];
        for (int k = 0; k < TOPK; k++) {
            float best = -1.f; int bi = 0;
            for (int e = 0; e < NE; e++)
                if (!((mask >> e) & 1u) && s[e] > best) { best = s[e]; bi = e; }
            mask |= 1u << bi; idxs[k] = bi; vals[k] = best; wsum += best;
        }
        wsum += 1e-6f;
        for (int k = 0; k < TOPK; k++) {
            tok_expert[t * TOPK + k] = idxs[k];
            tok_w[t * TOPK + k] = vals[k] / wsum;
            atomicAdd(&hist[idxs[k]], 1);
        }
    }
    __syncthreads();
    if (tid < NE) { int h = hist[tid]; if (h) atomicAdd(&ctrl[tid], h); }
    if (tid == NE) atomicAdd(aux, auxsh * (0.01f / 32768.0f));
}

__global__ void scan_kernel(int* __restrict__ ctrl) {
    if (threadIdx.x == 0) {
        int acc = 0;
        for (int e = 0; e < NE; e++) { ctrl[8 + e] = acc; acc += ctrl[e]; }
    }
}

__global__ __launch_bounds__(256) void assign_kernel(const int* __restrict__ tok_expert,
                                                     const float* __restrict__ tok_w,
                                                     int* __restrict__ ctrl,
                                                     int* __restrict__ pair_token,
                                                     int* __restrict__ tok_slot) {
    int t = blockIdx.x * blockDim.x + threadIdx.x;
    if (t >= T_TOK) return;
    for (int k = 0; k < TOPK; k++) {
        int e = tok_expert[t * TOPK + k];
        int pos = atomicAdd(&ctrl[16 + e], 1);
        int slot = ctrl[8 + e] + pos;
        pair_token[slot] = t;
        tok_slot[t * TOPK + k] = slot;
    }
}

// ---------------- GEMM1: hidden = silu(x@w1)*(x@w2), gathered rows ----------------
// 256-row tile x 128 cols per SwiGLU half, BK=64, 8 waves (2Mx4N).
// m201-style phases: reads issued BEFORE the pre-MFMA barrier (in flight across it);
// half-tile staging (vmcnt(4) twice per tile, never 0 until the tail); P2/P3 have no
// head sync so their reads/MFMAs overlap the previous cluster's pipe drain.
__global__ __launch_bounds__(512, 2) void gemm1_kernel(const u16* __restrict__ xb,
                                                       const u16* __restrict__ w12t,
                                                       const int* __restrict__ pair_token,
                                                       const int* __restrict__ ctrl,
                                                       u16* __restrict__ hidden) {
    const int e = blockIdx.z;
    const int cnt = ctrl[e];
    if ((int)blockIdx.y * 256 >= cnt) return;
    const int off = ctrl[8 + e];
    const int rowbase = off + blockIdx.y * 256;
    const int rowend = off + cnt;
    const int n0 = blockIdx.x * 128;   // col base within each half

    extern __shared__ __align__(16) u16 lds[];   // 2 slots x 32768 u16

    const int tid = threadIdx.x;
    const int wave = tid >> 6, lane = tid & 63;
    const int srow = tid >> 3;                       // 0..63 row-in-round
    const int scol = ((tid & 7) ^ (srow & 7)) * 8;   // pre-swizzled global col

    const u16* srcA[4];
    const u16* srcB[4];
#pragma unroll
    for (int r = 0; r < 4; ++r) {
        int sr = rowbase + r * 64 + srow;
        int tok = (sr < rowend) ? pair_token[sr] : 0;
        srcA[r] = xb + (size_t)tok * DIM + scol;
    }
#pragma unroll
    for (int r = 0; r < 2; ++r) {
        srcB[r]     = w12t + ((size_t)e * 2 * HID + n0 + r * 64 + srow) * DIM + scol; // w1
        srcB[r + 2] = srcB[r] + (size_t)HID * DIM;                                    // w2
    }

    const int wm = wave >> 2, wn = wave & 3;
    const int lrow = lane & 15, lq = lane >> 4, xm = lrow & 7;
    const int so0 = ((lq ^ xm) << 3);
    const int so1 = (((4 | lq) ^ xm) << 3);

    f32x4 acc0[8][2], acc1[8][2];
#pragma unroll
    for (int mf = 0; mf < 8; ++mf)
#pragma unroll
        for (int nf = 0; nf < 2; ++nf) { acc0[mf][nf] = (f32x4)0.f; acc1[mf][nf] = (f32x4)0.f; }

    // prologue: stage K-tile 0, halves in queue order [H0 = A02+B01, H1 = B23+A13]
    STAGE_A02(lds); STAGE_B01(lds);
    STAGE_B23(lds); STAGE_A13(lds);
    ADV();

    const int NT = DIM / 64;   // 16
    for (int kt = 0; kt < NT; ++kt) {
        u16* cur = lds + (kt & 1) * 32768;
        u16* nxt = lds + ((kt & 1) ^ 1) * 32768;
        const u16* sA = cur;
        const u16* sB = cur + 16384;
        const bool notlast = (kt < NT - 1);

        bf16x8 a[4][2], b0[2][2], b1[2][2];
        // ---- P0: H0(cur) visible; reads A-lo+B0; stage H0(next); bar; M0 ----
        VMCNT(4); SBAR; SCHED0;
#pragma unroll
        for (int mf = 0; mf < 4; ++mf) {
            const u16* base = sA + (wm * 128 + mf * 16 + lrow) * 64;
            a[mf][0] = *(const bf16x8*)(base + so0);
            a[mf][1] = *(const bf16x8*)(base + so1);
        }
#pragma unroll
        for (int nf = 0; nf < 2; ++nf) {
            const u16* base = sB + (wn * 32 + nf * 16 + lrow) * 64;
            b0[nf][0] = *(const bf16x8*)(base + so0);
            b0[nf][1] = *(const bf16x8*)(base + so1);
        }
        if (notlast) { STAGE_A02(nxt); STAGE_B01(nxt); }
        SCHED0; SBAR; LGKM0; SCHED0;
        PRIO1;
#pragma unroll
        for (int mf = 0; mf < 4; ++mf)
#pragma unroll
            for (int nf = 0; nf < 2; ++nf) {
                acc0[mf][nf] = __builtin_amdgcn_mfma_f32_16x16x32_bf16(a[mf][0], b0[nf][0], acc0[mf][nf], 0, 0, 0);
                acc0[mf][nf] = __builtin_amdgcn_mfma_f32_16x16x32_bf16(a[mf][1], b0[nf][1], acc0[mf][nf], 0, 0, 0);
            }
        PRIO0; SCHED0;
        // ---- P1: H1(cur) visible; reads B1; bar; M1 ----
        if (notlast) { VMCNT(4); } else { VMCNT(0); }
        SBAR; SCHED0;
#pragma unroll
        for (int nf = 0; nf < 2; ++nf) {
            const u16* base = sB + 128 * 64 + (wn * 32 + nf * 16 + lrow) * 64;
            b1[nf][0] = *(const bf16x8*)(base + so0);
            b1[nf][1] = *(const bf16x8*)(base + so1);
        }
        SCHED0; SBAR; LGKM0; SCHED0;
        PRIO1;
#pragma unroll
        for (int mf = 0; mf < 4; ++mf)
#pragma unroll
            for (int nf = 0; nf < 2; ++nf) {
                acc1[mf][nf] = __builtin_amdgcn_mfma_f32_16x16x32_bf16(a[mf][0], b1[nf][0], acc1[mf][nf], 0, 0, 0);
                acc1[mf][nf] = __builtin_amdgcn_mfma_f32_16x16x32_bf16(a[mf][1], b1[nf][1], acc1[mf][nf], 0, 0, 0);
            }
        PRIO0; SCHED0;
        // ---- P2: no head sync; reads A-hi (overlap M1 drain); stage H1(next); bar; M2 ----
#pragma unroll
        for (int mf = 0; mf < 4; ++mf) {
            const u16* base = sA + (wm * 128 + (mf + 4) * 16 + lrow) * 64;
            a[mf][0] = *(const bf16x8*)(base + so0);
            a[mf][1] = *(const bf16x8*)(base + so1);
        }
        if (notlast) { STAGE_B23(nxt); STAGE_A13(nxt); ADV(); }
        SCHED0; SBAR; LGKM0; SCHED0;
        PRIO1;
#pragma unroll
        for (int mf = 0; mf < 4; ++mf)
#pragma unroll
            for (int nf = 0; nf < 2; ++nf) {
                acc1[mf + 4][nf] = __builtin_amdgcn_mfma_f32_16x16x32_bf16(a[mf][0], b1[nf][0], acc1[mf + 4][nf], 0, 0, 0);
                acc1[mf + 4][nf] = __builtin_amdgcn_mfma_f32_16x16x32_bf16(a[mf][1], b1[nf][1], acc1[mf + 4][nf], 0, 0, 0);
            }
        PRIO0; SCHED0;
        // ---- P3: bar; M3 (regs only: A-hi + B0) ----
        SBAR;
        PRIO1;
#pragma unroll
        for (int mf = 0; mf < 4; ++mf)
#pragma unroll
            for (int nf = 0; nf < 2; ++nf) {
                acc0[mf + 4][nf] = __builtin_amdgcn_mfma_f32_16x16x32_bf16(a[mf][0], b0[nf][0], acc0[mf + 4][nf], 0, 0, 0);
                acc0[mf + 4][nf] = __builtin_amdgcn_mfma_f32_16x16x32_bf16(a[mf][1], b0[nf][1], acc0[mf + 4][nf], 0, 0, 0);
            }
        PRIO0; SCHED0;
    }

#pragma unroll
    for (int mf = 0; mf < 8; ++mf) {
        const int gr0 = rowbase + wm * 128 + mf * 16 + lq * 4;
#pragma unroll
        for (int nf = 0; nf < 2; ++nf) {
            const int gc = n0 + wn * 32 + nf * 16 + lrow;
#pragma unroll
            for (int r = 0; r < 4; ++r) {
                const int gr = gr0 + r;
                if (gr < rowend) {
                    float x1 = acc0[mf][nf][r], x2 = acc1[mf][nf][r];
                    float h = x1 / (1.f + __expf(-x1)) * x2;
                    hidden[(size_t)gr * HID + gc] = f2bf(h);
                }
            }
        }
    }
}

// ---------------- GEMM2: y = hidden @ w3 ----------------
// 256x256 tile, BK=64, 8 waves (2Mx4N), same m201-style phase schedule.
__global__ __launch_bounds__(512, 2) void gemm2_kernel(const u16* __restrict__ hidden,
                                                       const u16* __restrict__ w3t,
                                                       const int* __restrict__ ctrl,
                                                       float* __restrict__ ybuf) {
    const int e = blockIdx.z;
    const int cnt = ctrl[e];
    if ((int)blockIdx.y * 256 >= cnt) return;
    const int off = ctrl[8 + e];
    const int rowbase = off + blockIdx.y * 256;
    const int rowend = off + cnt;
    const int n0 = blockIdx.x * 256;

    extern __shared__ __align__(16) u16 lds[];

    const int tid = threadIdx.x;
    const int wave = tid >> 6, lane = tid & 63;
    const int srow = tid >> 3;
    const int scol = ((tid & 7) ^ (srow & 7)) * 8;

    const u16* srcA[4];
    const u16* srcB[4];
#pragma unroll
    for (int r = 0; r < 4; ++r) {
        int sr = rowbase + r * 64 + srow;
        if (sr > NPAIR - 1) sr = NPAIR - 1;
        srcA[r] = hidden + (size_t)sr * HID + scol;
        srcB[r] = w3t + ((size_t)e * DIM + n0 + r * 64 + srow) * HID + scol;
    }

    const int wm = wave >> 2, wn = wave & 3;
    const int lrow = lane & 15, lq = lane >> 4, xm = lrow & 7;
    const int so0 = ((lq ^ xm) << 3);
    const int so1 = (((4 | lq) ^ xm) << 3);

    f32x4 acc[8][4];
#pragma unroll
    for (int mf = 0; mf < 8; ++mf)
#pragma unroll
        for (int nf = 0; nf < 4; ++nf) acc[mf][nf] = (f32x4)0.f;

    STAGE_A02(lds); STAGE_B01(lds);
    STAGE_B23(lds); STAGE_A13(lds);
    ADV();

    const int NT = HID / 64;   // 64
    for (int kt = 0; kt < NT; ++kt) {
        u16* cur = lds + (kt & 1) * 32768;
        u16* nxt = lds + ((kt & 1) ^ 1) * 32768;
        const u16* sA = cur;
        const u16* sB = cur + 16384;
        const bool notlast = (kt < NT - 1);

        bf16x8 a[4][2], b[4][2];
        // ---- P0: H0 visible; reads A-lo + B[0..1]; stage H0(next); bar; M0 ----
        VMCNT(4); SBAR; SCHED0;
#pragma unroll
        for (int mf = 0; mf < 4; ++mf) {
            const u16* base = sA + (wm * 128 + mf * 16 + lrow) * 64;
            a[mf][0] = *(const bf16x8*)(base + so0);
            a[mf][1] = *(const bf16x8*)(base + so1);
        }
#pragma unroll
        for (int nf = 0; nf < 2; ++nf) {
            const u16* base = sB + (nf * 64 + wn * 16 + lrow) * 64;
            b[nf][0] = *(const bf16x8*)(base + so0);
            b[nf][1] = *(const bf16x8*)(base + so1);
        }
        if (notlast) { STAGE_A02(nxt); STAGE_B01(nxt); }
        SCHED0; SBAR; LGKM0; SCHED0;
        PRIO1;
#pragma unroll
        for (int mf = 0; mf < 4; ++mf)
#pragma unroll
            for (int nf = 0; nf < 2; ++nf) {
                acc[mf][nf] = __builtin_amdgcn_mfma_f32_16x16x32_bf16(a[mf][0], b[nf][0], acc[mf][nf], 0, 0, 0);
                acc[mf][nf] = __builtin_amdgcn_mfma_f32_16x16x32_bf16(a[mf][1], b[nf][1], acc[mf][nf], 0, 0, 0);
            }
        PRIO0; SCHED0;
        // ---- P1: H1 visible; reads B[2..3]; bar; M1 ----
        if (notlast) { VMCNT(4); } else { VMCNT(0); }
        SBAR; SCHED0;
#pragma unroll
        for (int nf = 2; nf < 4; ++nf) {
            const u16* base = sB + (nf * 64 + wn * 16 + lrow) * 64;
            b[nf][0] = *(const bf16x8*)(base + so0);
            b[nf][1] = *(const bf16x8*)(base + so1);
        }
        SCHED0; SBAR; LGKM0; SCHED0;
        PRIO1;
#pragma unroll
        for (int mf = 0; mf < 4; ++mf)
#pragma unroll
            for (int nf = 2; nf < 4; ++nf) {
                acc[mf][nf] = __builtin_amdgcn_mfma_f32_16x16x32_bf16(a[mf][0], b[nf][0], acc[mf][nf], 0, 0, 0);
                acc[mf][nf] = __builtin_amdgcn_mfma_f32_16x16x32_bf16(a[mf][1], b[nf][1], acc[mf][nf], 0, 0, 0);
            }
        PRIO0; SCHED0;
        // ---- P2: no head sync; reads A-hi; stage H1(next); bar; M2 ----
#pragma unroll
        for (int mf = 0; mf < 4; ++mf) {
            const u16* base = sA + (wm * 128 + (mf + 4) * 16 + lrow) * 64;
            a[mf][0] = *(const bf16x8*)(base + so0);
            a[mf][1] = *(const bf16x8*)(base + so1);
        }
        if (notlast) { STAGE_B23(nxt); STAGE_A13(nxt); ADV(); }
        SCHED0; SBAR; LGKM0; SCHED0;
        PRIO1;
#pragma unroll
        for (int mf = 0; mf < 4; ++mf)
#pragma unroll
            for (int nf = 2; nf < 4; ++nf) {
                acc[mf + 4][nf] = __builtin_amdgcn_mfma_f32_16x16x32_bf16(a[mf][0], b[nf][0], acc[mf + 4][nf], 0, 0, 0);
                acc[mf + 4][nf] = __builtin_amdgcn_mfma_f32_16x16x32_bf16(a[mf][1], b[nf][1], acc[mf + 4][nf], 0, 0, 0);
            }
        PRIO0; SCHED0;
        // ---- P3: bar; M3 (regs only: A-hi + B[0..1]) ----
        SBAR;
        PRIO1;
#pragma unroll
        for (int mf = 0; mf < 4; ++mf)
#pragma unroll
            for (int nf = 0; nf < 2; ++nf) {
                acc[mf + 4][nf] = __builtin_amdgcn_mfma_f32_16x16x32_bf16(a[mf][0], b[nf][0], acc[mf + 4][nf], 0, 0, 0);
                acc[mf + 4][nf] = __builtin_amdgcn_mfma_f32_16x16x32_bf16(a[mf][1], b[nf][1], acc[mf + 4][nf], 0, 0, 0);
            }
        PRIO0; SCHED0;
    }

#pragma unroll
    for (int mf = 0; mf < 8; ++mf) {
        const int gr0 = rowbase + wm * 128 + mf * 16 + lq * 4;
#pragma unroll
        for (int nf = 0; nf < 4; ++nf) {
            const int gc = n0 + nf * 64 + wn * 16 + lrow;
#pragma unroll
            for (int r = 0; r < 4; ++r) {
                const int gr = gr0 + r;
                if (gr < rowend) ybuf[(size_t)gr * DIM + gc] = acc[mf][nf][r];
            }
        }
    }
}

// ---------------- combine: out[t] = sum_k w_k * y[slot_k] ----------------
__global__ __launch_bounds__(256) void combine_kernel(const float* __restrict__ ybuf,
                                                      const int* __restrict__ tok_slot,
                                                      const float* __restrict__ tok_w,
                                                      float* __restrict__ out) {
    const int t = blockIdx.x;
    const int d = threadIdx.x * 4;
    const int s0 = tok_slot[t * 3 + 0], s1 = tok_slot[t * 3 + 1], s2 = tok_slot[t * 3 + 2];
    const float w0 = tok_w[t * 3 + 0], w1 = tok_w[t * 3 + 1], w2 = tok_w[t * 3 + 2];
    const float4 a0 = *(const float4*)(ybuf + (size_t)s0 * DIM + d);
    const float4 a1 = *(const float4*)(ybuf + (size_t)s1 * DIM + d);
    const float4 a2 = *(const float4*)(ybuf + (size_t)s2 * DIM + d);
    float4 o;
    o.x = w0 * a0.x + w1 * a1.x + w2 * a2.x;
    o.y = w0 * a0.y + w1 * a1.y + w2 * a2.y;
    o.z = w0 * a0.z + w1 * a1.z + w2 * a2.z;
    o.w = w0 * a0.w + w1 * a1.w + w2 * a2.w;
    *(float4*)(out + (size_t)t * DIM + d) = o;
}

extern "C" void kernel_launch(void* const* d_in, const int* in_sizes, int n_in,
                              void* d_out, int out_size, void* d_ws, size_t ws_size,
                              hipStream_t stream) {
    const float* x   = (const float*)d_in[0];
    const float* rw  = (const float*)d_in[1];
    const float* rb  = (const float*)d_in[2];
    const float* w12 = (const float*)d_in[3];
    const float* w3  = (const float*)d_in[4];
    float* out = (float*)d_out;
    char* ws = (char*)d_ws;

    int*   ctrl       = (int*)(ws + OFF_CTRL);
    u16*   xb         = (u16*)(ws + OFF_XB);
    u16*   w12t       = (u16*)(ws + OFF_W12T);
    u16*   w3t        = (u16*)(ws + OFF_W3T);
    u16*   hidden     = (u16*)(ws + OFF_HID);
    float* ybuf       = (float*)(ws + OFF_Y);
    int*   pair_token = (int*)(ws + OFF_PTOK);
    int*   tok_expert = (int*)(ws + OFF_TE);
    float* tok_w      = (float*)(ws + OFF_TW);
    int*   tok_slot   = (int*)(ws + OFF_TS);

    static bool attr_set = false;
    if (!attr_set) {
        hipFuncSetAttribute((const void*)gemm1_kernel, hipFuncAttributeMaxDynamicSharedMemorySize, 131072);
        hipFuncSetAttribute((const void*)gemm2_kernel, hipFuncAttributeMaxDynamicSharedMemorySize, 131072);
        attr_set = true;
    }

    hipMemsetAsync(ctrl, 0, 256, stream);
    hipMemsetAsync(out + (size_t)T_TOK * DIM, 0, sizeof(float), stream);  // aux slot

    router_kernel<<<T_TOK / 4, 256, 0, stream>>>(x, rw, rb, xb, tok_expert, tok_w, ctrl,
                                                 out + (size_t)T_TOK * DIM);
    transpose_cast_kernel<<<dim3(2 * HID / 32, DIM / 64, NE), 256, 0, stream>>>(w12, w12t, DIM, 2 * HID);
    transpose_cast_kernel<<<dim3(DIM / 32, HID / 64, NE), 256, 0, stream>>>(w3, w3t, HID, DIM);
    scan_kernel<<<1, 64, 0, stream>>>(ctrl);
    assign_kernel<<<16, 256, 0, stream>>>(tok_expert, tok_w, ctrl, pair_token, tok_slot);

    gemm1_kernel<<<dim3(HID / 128, 16, NE), 512, 131072, stream>>>(xb, w12t, pair_token, ctrl, hidden);
    gemm2_kernel<<<dim3(DIM / 256, 16, NE), 512, 131072, stream>>>(hidden, w3t, ctrl, ybuf);
    combine_kernel<<<T_TOK, 256, 0, stream>>>(ybuf, tok_slot, tok_w, out);
    (void)in_sizes; (void)n_in; (void)out_size; (void)ws_size;
}

// Round 4
// 879.632 us; speedup vs baseline: 1.0307x; 1.0307x over previous
//
#include <hip/hip_runtime.h>
#include <math.h>

typedef unsigned short u16;
typedef __bf16 bf16x8 __attribute__((ext_vector_type(8)));
typedef float f32x4 __attribute__((ext_vector_type(4)));

#define T_TOK 4096
#define DIM   1024
#define HID   4096
#define NE    8
#define TOPK  3
#define NPAIR 12288   // T_TOK * TOPK

// ---------------- ws layout (bytes) ----------------
// ctrl ints: [0..7]=ecnt, [16..23]=efill
constexpr size_t OFF_CTRL = 0;
constexpr size_t OFF_XB   = 256;
constexpr size_t OFF_W12T = OFF_XB   + (size_t)T_TOK * DIM * 2;
constexpr size_t OFF_W3T  = OFF_W12T + (size_t)NE * 2 * HID * DIM * 2;
constexpr size_t OFF_HID  = OFF_W3T  + (size_t)NE * DIM * HID * 2;
constexpr size_t OFF_Y    = OFF_HID  + (size_t)NPAIR * HID * 2;
constexpr size_t OFF_PTOK = OFF_Y    + (size_t)NPAIR * DIM * 4;
constexpr size_t OFF_TE   = OFF_PTOK + (size_t)NPAIR * 4;
constexpr size_t OFF_TW   = OFF_TE   + (size_t)T_TOK * TOPK * 4;
constexpr size_t OFF_TS   = OFF_TW   + (size_t)T_TOK * TOPK * 4;

__device__ __forceinline__ u16 f2bf(float f) {
    unsigned u = __builtin_bit_cast(unsigned, f);
    u += 0x7fffu + ((u >> 16) & 1u);   // RNE
    return (u16)(u >> 16);
}

// async global->LDS DMA, 16B per lane; LDS dst = wave-uniform base + lane*16
__device__ __forceinline__ void ld_g2l(const u16* g, u16* l) {
    __builtin_amdgcn_global_load_lds((__attribute__((address_space(1))) unsigned*)(g),
                                     (__attribute__((address_space(3))) unsigned*)(l),
                                     16, 0, 0);
}

// raw sync primitives: raw s_barrier does NOT drain vmcnt (that's the point)
#define VMCNT(N) asm volatile("s_waitcnt vmcnt(" #N ")" ::: "memory")
#define SBAR   __builtin_amdgcn_s_barrier()
#define PRIO1  __builtin_amdgcn_s_setprio(1)
#define PRIO0  __builtin_amdgcn_s_setprio(0)

// quarter staging macros (2 global_load_lds each)
#define STAGE_A02(dst) { ld_g2l(srcA[0], (dst) + (0 * 64 + wave * 8) * 64); \
                         ld_g2l(srcA[2], (dst) + (2 * 64 + wave * 8) * 64); }
#define STAGE_B01(dst) { ld_g2l(srcB[0], (dst) + 16384 + (0 * 64 + wave * 8) * 64); \
                         ld_g2l(srcB[1], (dst) + 16384 + (1 * 64 + wave * 8) * 64); }
#define STAGE_B23(dst) { ld_g2l(srcB[2], (dst) + 16384 + (2 * 64 + wave * 8) * 64); \
                         ld_g2l(srcB[3], (dst) + 16384 + (3 * 64 + wave * 8) * 64); }
#define STAGE_A13(dst) { ld_g2l(srcA[1], (dst) + (1 * 64 + wave * 8) * 64); \
                         ld_g2l(srcA[3], (dst) + (3 * 64 + wave * 8) * 64); }
#define ADV()          { _Pragma("unroll") \
                         for (int r_ = 0; r_ < 4; ++r_) { srcA[r_] += 64; srcB[r_] += 64; } }

// ---------------- transpose-cast: [E][K][N] fp32 -> [E][N][K] bf16 ----------------
__global__ __launch_bounds__(256) void transpose_cast_kernel(const float* __restrict__ in,
                                                             u16* __restrict__ out, int K, int N) {
    __shared__ float tile[64][33];
    const float* inp = in + (size_t)blockIdx.z * K * N;
    u16* outp = out + (size_t)blockIdx.z * K * N;
    const int n0 = blockIdx.x * 32, k0 = blockIdx.y * 64;
    const int tid = threadIdx.x;
#pragma unroll
    for (int i = 0; i < 2; ++i) {
        int k = i * 32 + (tid >> 3);
        int c4 = (tid & 7) * 4;
        float4 f = *(const float4*)(inp + (size_t)(k0 + k) * N + n0 + c4);
        tile[k][c4 + 0] = f.x; tile[k][c4 + 1] = f.y;
        tile[k][c4 + 2] = f.z; tile[k][c4 + 3] = f.w;
    }
    __syncthreads();
    const int n = tid >> 3, c = (tid & 7) * 8;
    u16 buf[8];
#pragma unroll
    for (int j = 0; j < 8; ++j) buf[j] = f2bf(tile[c + j][n]);
    *(uint4*)(outp + (size_t)(n0 + n) * K + k0 + c) = *(uint4*)buf;
}

// ---------------- router (fused x->bf16 cast, block-level atomics) ----------------
__global__ __launch_bounds__(256) void router_kernel(const float* __restrict__ x,
                                                     const float* __restrict__ rw,
                                                     const float* __restrict__ rb,
                                                     u16* __restrict__ xb,
                                                     int* __restrict__ tok_expert,
                                                     float* __restrict__ tok_w,
                                                     int* __restrict__ ctrl,
                                                     float* __restrict__ aux) {
    __shared__ int hist[NE];
    __shared__ float auxsh;
    const int tid = threadIdx.x;
    if (tid < NE) hist[tid] = 0;
    if (tid == NE) auxsh = 0.f;
    __syncthreads();

    const int wave = tid >> 6, lane = tid & 63;
    const int t = blockIdx.x * 4 + wave;
    const float* xr = x + (size_t)t * DIM;
    u16* xbr = xb + (size_t)t * DIM;

    float p[NE];
#pragma unroll
    for (int e = 0; e < NE; e++) p[e] = 0.f;
#pragma unroll
    for (int q = 0; q < 4; ++q) {
        const int d = q * 256 + lane * 4;
        float4 f = *(const float4*)(xr + d);
        uint2 v;
        v.x = (unsigned)f2bf(f.x) | ((unsigned)f2bf(f.y) << 16);
        v.y = (unsigned)f2bf(f.z) | ((unsigned)f2bf(f.w) << 16);
        *(uint2*)(xbr + d) = v;
#pragma unroll
        for (int e = 0; e < NE; e++) {
            float4 w = *(const float4*)(rw + e * DIM + d);
            p[e] += f.x * w.x + f.y * w.y + f.z * w.z + f.w * w.w;
        }
    }
#pragma unroll
    for (int e = 0; e < NE; e++) {
#pragma unroll
        for (int off = 32; off; off >>= 1) p[e] += __shfl_down(p[e], off, 64);
    }
    if (lane == 0) {
        float s[NE]; float auxs = 0.f;
#pragma unroll
        for (int e = 0; e < NE; e++) {
            float lg = p[e] + rb[e];
            auxs += lg * lg;
            s[e] = 1.f / (1.f + __expf(-lg));
        }
        atomicAdd(&auxsh, auxs);
        unsigned mask = 0; float wsum = 0.f;
        int idxs[TOPK]; float vals[TOPK];
        for (int k = 0; k < TOPK; k++) {
            float best = -1.f; int bi = 0;
            for (int e = 0; e < NE; e++)
                if (!((mask >> e) & 1u) && s[e] > best) { best = s[e]; bi = e; }
            mask |= 1u << bi; idxs[k] = bi; vals[k] = best; wsum += best;
        }
        wsum += 1e-6f;
        for (int k = 0; k < TOPK; k++) {
            tok_expert[t * TOPK + k] = idxs[k];
            tok_w[t * TOPK + k] = vals[k] / wsum;
            atomicAdd(&hist[idxs[k]], 1);
        }
    }
    __syncthreads();
    if (tid < NE) { int h = hist[tid]; if (h) atomicAdd(&ctrl[tid], h); }
    if (tid == NE) atomicAdd(aux, auxsh * (0.01f / 32768.0f));
}

// assign: prefix computed locally from ctrl[0..7] (scan kernel removed)
__global__ __launch_bounds__(256) void assign_kernel(const int* __restrict__ tok_expert,
                                                     const float* __restrict__ tok_w,
                                                     int* __restrict__ ctrl,
                                                     int* __restrict__ pair_token,
                                                     int* __restrict__ tok_slot) {
    __shared__ int soff[NE];
    if (threadIdx.x < NE) {
        int acc = 0;
        for (int i = 0; i < (int)threadIdx.x; ++i) acc += ctrl[i];
        soff[threadIdx.x] = acc;
    }
    __syncthreads();
    int t = blockIdx.x * blockDim.x + threadIdx.x;
    if (t >= T_TOK) return;
    for (int k = 0; k < TOPK; k++) {
        int e = tok_expert[t * TOPK + k];
        int pos = atomicAdd(&ctrl[16 + e], 1);
        int slot = soff[e] + pos;
        pair_token[slot] = t;
        tok_slot[t * TOPK + k] = slot;
    }
}

// ---------------- GEMM1: hidden = silu(x@w1)*(x@w2), gathered rows ----------------
// 256-row tile x 128 cols per SwiGLU half, BK=64, 8 waves (2Mx4N).
// Round-2 skeleton (quarter staging, counted vmcnt 4/6/6, one barrier per phase)
// WITHOUT lgkmcnt(0)/sched_barrier walls: the compiler emits counted lgkmcnt so
// MFMAs start as soon as their own operands land, draining the rest of the phase's
// ds_reads under MFMA execution.
__global__ __launch_bounds__(512, 2) void gemm1_kernel(const u16* __restrict__ xb,
                                                       const u16* __restrict__ w12t,
                                                       const int* __restrict__ pair_token,
                                                       const int* __restrict__ ctrl,
                                                       u16* __restrict__ hidden) {
    const int e = blockIdx.z;
    const int cnt = ctrl[e];
    if ((int)blockIdx.y * 256 >= cnt) return;
    int off = 0;
    for (int i = 0; i < e; ++i) off += ctrl[i];
    const int rowbase = off + blockIdx.y * 256;
    const int rowend = off + cnt;
    const int n0 = blockIdx.x * 128;   // col base within each half

    extern __shared__ __align__(16) u16 lds[];   // 2 slots x 32768 u16

    const int tid = threadIdx.x;
    const int wave = tid >> 6, lane = tid & 63;
    const int srow = tid >> 3;                       // 0..63 row-in-round
    const int scol = ((tid & 7) ^ (srow & 7)) * 8;   // pre-swizzled global col

    const u16* srcA[4];
    const u16* srcB[4];
#pragma unroll
    for (int r = 0; r < 4; ++r) {
        int sr = rowbase + r * 64 + srow;
        int tok = (sr < rowend) ? pair_token[sr] : 0;
        srcA[r] = xb + (size_t)tok * DIM + scol;
    }
#pragma unroll
    for (int r = 0; r < 2; ++r) {
        srcB[r]     = w12t + ((size_t)e * 2 * HID + n0 + r * 64 + srow) * DIM + scol; // w1
        srcB[r + 2] = srcB[r] + (size_t)HID * DIM;                                    // w2
    }

    const int wm = wave >> 2, wn = wave & 3;
    const int lrow = lane & 15, lq = lane >> 4, xm = lrow & 7;
    const int so0 = ((lq ^ xm) << 3);
    const int so1 = (((4 | lq) ^ xm) << 3);

    f32x4 acc0[8][2], acc1[8][2];
#pragma unroll
    for (int mf = 0; mf < 8; ++mf)
#pragma unroll
        for (int nf = 0; nf < 2; ++nf) { acc0[mf][nf] = (f32x4)0.f; acc1[mf][nf] = (f32x4)0.f; }

    // prologue: stage K-tile 0 in queue order [p0-set(4), p1-set(2), p2-set(2)]
    STAGE_A02(lds); STAGE_B01(lds);
    STAGE_B23(lds);
    STAGE_A13(lds);
    ADV();

    const int NT = DIM / 64;   // 16
    for (int kt = 0; kt < NT; ++kt) {
        u16* cur = lds + (kt & 1) * 32768;
        u16* nxt = lds + ((kt & 1) ^ 1) * 32768;
        const u16* sA = cur;
        const u16* sB = cur + 16384;
        const bool notlast = (kt < NT - 1);

        bf16x8 a[4][2], b0[2][2], b1[2][2];
        // ---- phase 0: wait p0-set; read A-lo + B0; issue next p0-set; MFMA ----
        VMCNT(4); SBAR;
#pragma unroll
        for (int mf = 0; mf < 4; ++mf) {
            const u16* base = sA + (wm * 128 + mf * 16 + lrow) * 64;
            a[mf][0] = *(const bf16x8*)(base + so0);
            a[mf][1] = *(const bf16x8*)(base + so1);
        }
#pragma unroll
        for (int nf = 0; nf < 2; ++nf) {
            const u16* base = sB + (wn * 32 + nf * 16 + lrow) * 64;
            b0[nf][0] = *(const bf16x8*)(base + so0);
            b0[nf][1] = *(const bf16x8*)(base + so1);
        }
        if (notlast) { STAGE_A02(nxt); STAGE_B01(nxt); }
        PRIO1;
#pragma unroll
        for (int mf = 0; mf < 4; ++mf)
#pragma unroll
            for (int nf = 0; nf < 2; ++nf) {
                acc0[mf][nf] = __builtin_amdgcn_mfma_f32_16x16x32_bf16(a[mf][0], b0[nf][0], acc0[mf][nf], 0, 0, 0);
                acc0[mf][nf] = __builtin_amdgcn_mfma_f32_16x16x32_bf16(a[mf][1], b0[nf][1], acc0[mf][nf], 0, 0, 0);
            }
        PRIO0;
        // ---- phase 1: wait p1-set; read B1; issue next p1-set; MFMA ----
        if (notlast) { VMCNT(6); } else { VMCNT(2); }
        SBAR;
#pragma unroll
        for (int nf = 0; nf < 2; ++nf) {
            const u16* base = sB + 128 * 64 + (wn * 32 + nf * 16 + lrow) * 64;
            b1[nf][0] = *(const bf16x8*)(base + so0);
            b1[nf][1] = *(const bf16x8*)(base + so1);
        }
        if (notlast) STAGE_B23(nxt);
        PRIO1;
#pragma unroll
        for (int mf = 0; mf < 4; ++mf)
#pragma unroll
            for (int nf = 0; nf < 2; ++nf) {
                acc1[mf][nf] = __builtin_amdgcn_mfma_f32_16x16x32_bf16(a[mf][0], b1[nf][0], acc1[mf][nf], 0, 0, 0);
                acc1[mf][nf] = __builtin_amdgcn_mfma_f32_16x16x32_bf16(a[mf][1], b1[nf][1], acc1[mf][nf], 0, 0, 0);
            }
        PRIO0;
        // ---- phase 2: wait p2-set; read A-hi; issue next p2-set; MFMA ----
        if (notlast) { VMCNT(6); } else { VMCNT(0); }
        SBAR;
#pragma unroll
        for (int mf = 0; mf < 4; ++mf) {
            const u16* base = sA + (wm * 128 + (mf + 4) * 16 + lrow) * 64;
            a[mf][0] = *(const bf16x8*)(base + so0);
            a[mf][1] = *(const bf16x8*)(base + so1);
        }
        if (notlast) { STAGE_A13(nxt); ADV(); }
        PRIO1;
#pragma unroll
        for (int mf = 0; mf < 4; ++mf)
#pragma unroll
            for (int nf = 0; nf < 2; ++nf) {
                acc1[mf + 4][nf] = __builtin_amdgcn_mfma_f32_16x16x32_bf16(a[mf][0], b1[nf][0], acc1[mf + 4][nf], 0, 0, 0);
                acc1[mf + 4][nf] = __builtin_amdgcn_mfma_f32_16x16x32_bf16(a[mf][1], b1[nf][1], acc1[mf + 4][nf], 0, 0, 0);
            }
        PRIO0;
        // ---- phase 3: no reads, no waits (reuse A-hi + B0) ----
        SBAR;
        PRIO1;
#pragma unroll
        for (int mf = 0; mf < 4; ++mf)
#pragma unroll
            for (int nf = 0; nf < 2; ++nf) {
                acc0[mf + 4][nf] = __builtin_amdgcn_mfma_f32_16x16x32_bf16(a[mf][0], b0[nf][0], acc0[mf + 4][nf], 0, 0, 0);
                acc0[mf + 4][nf] = __builtin_amdgcn_mfma_f32_16x16x32_bf16(a[mf][1], b0[nf][1], acc0[mf + 4][nf], 0, 0, 0);
            }
        PRIO0;
    }

#pragma unroll
    for (int mf = 0; mf < 8; ++mf) {
        const int gr0 = rowbase + wm * 128 + mf * 16 + lq * 4;
#pragma unroll
        for (int nf = 0; nf < 2; ++nf) {
            const int gc = n0 + wn * 32 + nf * 16 + lrow;
#pragma unroll
            for (int r = 0; r < 4; ++r) {
                const int gr = gr0 + r;
                if (gr < rowend) {
                    float x1 = acc0[mf][nf][r], x2 = acc1[mf][nf][r];
                    float h = x1 / (1.f + __expf(-x1)) * x2;
                    hidden[(size_t)gr * HID + gc] = f2bf(h);
                }
            }
        }
    }
}

// ---------------- GEMM2: y = hidden @ w3 ----------------
// 256x256 tile, BK=64, 8 waves (2Mx4N), same counted-vmcnt schedule without walls.
// N-fragments stride-64 (gc = nf*64 + wn*16 + lrow) so B-reads align with quarters.
__global__ __launch_bounds__(512, 2) void gemm2_kernel(const u16* __restrict__ hidden,
                                                       const u16* __restrict__ w3t,
                                                       const int* __restrict__ ctrl,
                                                       float* __restrict__ ybuf) {
    const int e = blockIdx.z;
    const int cnt = ctrl[e];
    if ((int)blockIdx.y * 256 >= cnt) return;
    int off = 0;
    for (int i = 0; i < e; ++i) off += ctrl[i];
    const int rowbase = off + blockIdx.y * 256;
    const int rowend = off + cnt;
    const int n0 = blockIdx.x * 256;

    extern __shared__ __align__(16) u16 lds[];

    const int tid = threadIdx.x;
    const int wave = tid >> 6, lane = tid & 63;
    const int srow = tid >> 3;
    const int scol = ((tid & 7) ^ (srow & 7)) * 8;

    const u16* srcA[4];
    const u16* srcB[4];
#pragma unroll
    for (int r = 0; r < 4; ++r) {
        int sr = rowbase + r * 64 + srow;
        if (sr > NPAIR - 1) sr = NPAIR - 1;
        srcA[r] = hidden + (size_t)sr * HID + scol;
        srcB[r] = w3t + ((size_t)e * DIM + n0 + r * 64 + srow) * HID + scol;
    }

    const int wm = wave >> 2, wn = wave & 3;
    const int lrow = lane & 15, lq = lane >> 4, xm = lrow & 7;
    const int so0 = ((lq ^ xm) << 3);
    const int so1 = (((4 | lq) ^ xm) << 3);

    f32x4 acc[8][4];
#pragma unroll
    for (int mf = 0; mf < 8; ++mf)
#pragma unroll
        for (int nf = 0; nf < 4; ++nf) acc[mf][nf] = (f32x4)0.f;

    STAGE_A02(lds); STAGE_B01(lds);
    STAGE_B23(lds);
    STAGE_A13(lds);
    ADV();

    const int NT = HID / 64;   // 64
    for (int kt = 0; kt < NT; ++kt) {
        u16* cur = lds + (kt & 1) * 32768;
        u16* nxt = lds + ((kt & 1) ^ 1) * 32768;
        const u16* sA = cur;
        const u16* sB = cur + 16384;
        const bool notlast = (kt < NT - 1);

        bf16x8 a[4][2], b[4][2];
        // ---- phase 0: wait p0-set; read A-lo + B[0..1]; issue next p0-set; MFMA ----
        VMCNT(4); SBAR;
#pragma unroll
        for (int mf = 0; mf < 4; ++mf) {
            const u16* base = sA + (wm * 128 + mf * 16 + lrow) * 64;
            a[mf][0] = *(const bf16x8*)(base + so0);
            a[mf][1] = *(const bf16x8*)(base + so1);
        }
#pragma unroll
        for (int nf = 0; nf < 2; ++nf) {
            const u16* base = sB + (nf * 64 + wn * 16 + lrow) * 64;
            b[nf][0] = *(const bf16x8*)(base + so0);
            b[nf][1] = *(const bf16x8*)(base + so1);
        }
        if (notlast) { STAGE_A02(nxt); STAGE_B01(nxt); }
        PRIO1;
#pragma unroll
        for (int mf = 0; mf < 4; ++mf)
#pragma unroll
            for (int nf = 0; nf < 2; ++nf) {
                acc[mf][nf] = __builtin_amdgcn_mfma_f32_16x16x32_bf16(a[mf][0], b[nf][0], acc[mf][nf], 0, 0, 0);
                acc[mf][nf] = __builtin_amdgcn_mfma_f32_16x16x32_bf16(a[mf][1], b[nf][1], acc[mf][nf], 0, 0, 0);
            }
        PRIO0;
        // ---- phase 1: wait p1-set; read B[2..3]; issue next p1-set; MFMA ----
        if (notlast) { VMCNT(6); } else { VMCNT(2); }
        SBAR;
#pragma unroll
        for (int nf = 2; nf < 4; ++nf) {
            const u16* base = sB + (nf * 64 + wn * 16 + lrow) * 64;
            b[nf][0] = *(const bf16x8*)(base + so0);
            b[nf][1] = *(const bf16x8*)(base + so1);
        }
        if (notlast) STAGE_B23(nxt);
        PRIO1;
#pragma unroll
        for (int mf = 0; mf < 4; ++mf)
#pragma unroll
            for (int nf = 2; nf < 4; ++nf) {
                acc[mf][nf] = __builtin_amdgcn_mfma_f32_16x16x32_bf16(a[mf][0], b[nf][0], acc[mf][nf], 0, 0, 0);
                acc[mf][nf] = __builtin_amdgcn_mfma_f32_16x16x32_bf16(a[mf][1], b[nf][1], acc[mf][nf], 0, 0, 0);
            }
        PRIO0;
        // ---- phase 2: wait p2-set; read A-hi; issue next p2-set; MFMA ----
        if (notlast) { VMCNT(6); } else { VMCNT(0); }
        SBAR;
#pragma unroll
        for (int mf = 0; mf < 4; ++mf) {
            const u16* base = sA + (wm * 128 + (mf + 4) * 16 + lrow) * 64;
            a[mf][0] = *(const bf16x8*)(base + so0);
            a[mf][1] = *(const bf16x8*)(base + so1);
        }
        if (notlast) { STAGE_A13(nxt); ADV(); }
        PRIO1;
#pragma unroll
        for (int mf = 0; mf < 4; ++mf)
#pragma unroll
            for (int nf = 2; nf < 4; ++nf) {
                acc[mf + 4][nf] = __builtin_amdgcn_mfma_f32_16x16x32_bf16(a[mf][0], b[nf][0], acc[mf + 4][nf], 0, 0, 0);
                acc[mf + 4][nf] = __builtin_amdgcn_mfma_f32_16x16x32_bf16(a[mf][1], b[nf][1], acc[mf + 4][nf], 0, 0, 0);
            }
        PRIO0;
        // ---- phase 3: no reads, no waits (A-hi + B[0..1]) ----
        SBAR;
        PRIO1;
#pragma unroll
        for (int mf = 0; mf < 4; ++mf)
#pragma unroll
            for (int nf = 0; nf < 2; ++nf) {
                acc[mf + 4][nf] = __builtin_amdgcn_mfma_f32_16x16x32_bf16(a[mf][0], b[nf][0], acc[mf + 4][nf], 0, 0, 0);
                acc[mf + 4][nf] = __builtin_amdgcn_mfma_f32_16x16x32_bf16(a[mf][1], b[nf][1], acc[mf + 4][nf], 0, 0, 0);
            }
        PRIO0;
    }

#pragma unroll
    for (int mf = 0; mf < 8; ++mf) {
        const int gr0 = rowbase + wm * 128 + mf * 16 + lq * 4;
#pragma unroll
        for (int nf = 0; nf < 4; ++nf) {
            const int gc = n0 + nf * 64 + wn * 16 + lrow;
#pragma unroll
            for (int r = 0; r < 4; ++r) {
                const int gr = gr0 + r;
                if (gr < rowend) ybuf[(size_t)gr * DIM + gc] = acc[mf][nf][r];
            }
        }
    }
}

// ---------------- combine: out[t] = sum_k w_k * y[slot_k] ----------------
__global__ __launch_bounds__(256) void combine_kernel(const float* __restrict__ ybuf,
                                                      const int* __restrict__ tok_slot,
                                                      const float* __restrict__ tok_w,
                                                      float* __restrict__ out) {
    const int t = blockIdx.x;
    const int d = threadIdx.x * 4;
    const int s0 = tok_slot[t * 3 + 0], s1 = tok_slot[t * 3 + 1], s2 = tok_slot[t * 3 + 2];
    const float w0 = tok_w[t * 3 + 0], w1 = tok_w[t * 3 + 1], w2 = tok_w[t * 3 + 2];
    const float4 a0 = *(const float4*)(ybuf + (size_t)s0 * DIM + d);
    const float4 a1 = *(const float4*)(ybuf + (size_t)s1 * DIM + d);
    const float4 a2 = *(const float4*)(ybuf + (size_t)s2 * DIM + d);
    float4 o;
    o.x = w0 * a0.x + w1 * a1.x + w2 * a2.x;
    o.y = w0 * a0.y + w1 * a1.y + w2 * a2.y;
    o.z = w0 * a0.z + w1 * a1.z + w2 * a2.z;
    o.w = w0 * a0.w + w1 * a1.w + w2 * a2.w;
    *(float4*)(out + (size_t)t * DIM + d) = o;
}

extern "C" void kernel_launch(void* const* d_in, const int* in_sizes, int n_in,
                              void* d_out, int out_size, void* d_ws, size_t ws_size,
                              hipStream_t stream) {
    const float* x   = (const float*)d_in[0];
    const float* rw  = (const float*)d_in[1];
    const float* rb  = (const float*)d_in[2];
    const float* w12 = (const float*)d_in[3];
    const float* w3  = (const float*)d_in[4];
    float* out = (float*)d_out;
    char* ws = (char*)d_ws;

    int*   ctrl       = (int*)(ws + OFF_CTRL);
    u16*   xb         = (u16*)(ws + OFF_XB);
    u16*   w12t       = (u16*)(ws + OFF_W12T);
    u16*   w3t        = (u16*)(ws + OFF_W3T);
    u16*   hidden     = (u16*)(ws + OFF_HID);
    float* ybuf       = (float*)(ws + OFF_Y);
    int*   pair_token = (int*)(ws + OFF_PTOK);
    int*   tok_expert = (int*)(ws + OFF_TE);
    float* tok_w      = (float*)(ws + OFF_TW);
    int*   tok_slot   = (int*)(ws + OFF_TS);

    static bool attr_set = false;
    if (!attr_set) {
        hipFuncSetAttribute((const void*)gemm1_kernel, hipFuncAttributeMaxDynamicSharedMemorySize, 131072);
        hipFuncSetAttribute((const void*)gemm2_kernel, hipFuncAttributeMaxDynamicSharedMemorySize, 131072);
        attr_set = true;
    }

    hipMemsetAsync(ctrl, 0, 256, stream);
    hipMemsetAsync(out + (size_t)T_TOK * DIM, 0, sizeof(float), stream);  // aux slot

    router_kernel<<<T_TOK / 4, 256, 0, stream>>>(x, rw, rb, xb, tok_expert, tok_w, ctrl,
                                                 out + (size_t)T_TOK * DIM);
    transpose_cast_kernel<<<dim3(2 * HID / 32, DIM / 64, NE), 256, 0, stream>>>(w12, w12t, DIM, 2 * HID);
    transpose_cast_kernel<<<dim3(DIM / 32, HID / 64, NE), 256, 0, stream>>>(w3, w3t, HID, DIM);
    assign_kernel<<<16, 256, 0, stream>>>(tok_expert, tok_w, ctrl, pair_token, tok_slot);

    gemm1_kernel<<<dim3(HID / 128, 16, NE), 512, 131072, stream>>>(xb, w12t, pair_token, ctrl, hidden);
    gemm2_kernel<<<dim3(DIM / 256, 16, NE), 512, 131072, stream>>>(hidden, w3t, ctrl, ybuf);
    combine_kernel<<<T_TOK, 256, 0, stream>>>(ybuf, tok_slot, tok_w, out);
    (void)in_sizes; (void)n_in; (void)out_size; (void)ws_size;
}

// Round 5
// 821.612 us; speedup vs baseline: 1.1034x; 1.0706x over previous
//
#include <hip/hip_runtime.h>
#include <math.h>

typedef unsigned short u16;
typedef __bf16 bf16x8 __attribute__((ext_vector_type(8)));
typedef float f32x4 __attribute__((ext_vector_type(4)));

#define T_TOK 4096
#define DIM   1024
#define HID   4096
#define NE    8
#define TOPK  3
#define NPAIR 12288   // T_TOK * TOPK

// ---------------- ws layout (bytes) ----------------
// ctrl ints: [0..7]=ecnt, [16..23]=efill
constexpr size_t OFF_CTRL = 0;
constexpr size_t OFF_XB   = 256;
constexpr size_t OFF_W12T = OFF_XB   + (size_t)T_TOK * DIM * 2;
constexpr size_t OFF_W3T  = OFF_W12T + (size_t)NE * 2 * HID * DIM * 2;
constexpr size_t OFF_HID  = OFF_W3T  + (size_t)NE * DIM * HID * 2;
constexpr size_t OFF_Y    = OFF_HID  + (size_t)NPAIR * HID * 2;
constexpr size_t OFF_PTOK = OFF_Y    + (size_t)NPAIR * DIM * 4;
constexpr size_t OFF_TE   = OFF_PTOK + (size_t)NPAIR * 4;
constexpr size_t OFF_TW   = OFF_TE   + (size_t)T_TOK * TOPK * 4;
constexpr size_t OFF_TS   = OFF_TW   + (size_t)T_TOK * TOPK * 4;

__device__ __forceinline__ u16 f2bf(float f) {
    unsigned u = __builtin_bit_cast(unsigned, f);
    u += 0x7fffu + ((u >> 16) & 1u);   // RNE
    return (u16)(u >> 16);
}

// async global->LDS DMA, 16B per lane; LDS dst = wave-uniform base + lane*16
__device__ __forceinline__ void ld_g2l(const u16* g, u16* l) {
    __builtin_amdgcn_global_load_lds((__attribute__((address_space(1))) unsigned*)(g),
                                     (__attribute__((address_space(3))) unsigned*)(l),
                                     16, 0, 0);
}

// raw sync primitives: raw s_barrier does NOT drain vmcnt (that's the point)
#define VMCNT(N) asm volatile("s_waitcnt vmcnt(" #N ")" ::: "memory")
#define LGKM0  asm volatile("s_waitcnt lgkmcnt(0)" ::: "memory")
#define SBAR   __builtin_amdgcn_s_barrier()
#define SCHED0 __builtin_amdgcn_sched_barrier(0)
#define PRIO1  __builtin_amdgcn_s_setprio(1)
#define PRIO0  __builtin_amdgcn_s_setprio(0)

// quarter staging macros (2 global_load_lds each)
#define STAGE_A02(dst) { ld_g2l(srcA[0], (dst) + (0 * 64 + wave * 8) * 64); \
                         ld_g2l(srcA[2], (dst) + (2 * 64 + wave * 8) * 64); }
#define STAGE_B01(dst) { ld_g2l(srcB[0], (dst) + 16384 + (0 * 64 + wave * 8) * 64); \
                         ld_g2l(srcB[1], (dst) + 16384 + (1 * 64 + wave * 8) * 64); }
#define STAGE_B23(dst) { ld_g2l(srcB[2], (dst) + 16384 + (2 * 64 + wave * 8) * 64); \
                         ld_g2l(srcB[3], (dst) + 16384 + (3 * 64 + wave * 8) * 64); }
#define STAGE_A13(dst) { ld_g2l(srcA[1], (dst) + (1 * 64 + wave * 8) * 64); \
                         ld_g2l(srcA[3], (dst) + (3 * 64 + wave * 8) * 64); }
#define ADV()          { _Pragma("unroll") \
                         for (int r_ = 0; r_ < 4; ++r_) { srcA[r_] += 64; srcB[r_] += 64; } }

// ---------------- transpose-cast: [E][K][N] fp32 -> [E][N][K] bf16 ----------------
// 64x64 tile: 256B read segments, float4 LDS writes, 32B/thread contiguous stores.
__global__ __launch_bounds__(256) void transpose_cast_kernel(const float* __restrict__ in,
                                                             u16* __restrict__ out, int K, int N) {
    __shared__ float tile[64][68];
    const float* inp = in + (size_t)blockIdx.z * K * N;
    u16* outp = out + (size_t)blockIdx.z * K * N;
    const int n0 = blockIdx.x * 64, k0 = blockIdx.y * 64;
    const int tid = threadIdx.x;
    const int kr = tid >> 4;          // 0..15
    const int nc4 = (tid & 15) * 4;   // 0,4,..,60
#pragma unroll
    for (int i = 0; i < 4; ++i) {
        const int k = i * 16 + kr;
        float4 f = *(const float4*)(inp + (size_t)(k0 + k) * N + n0 + nc4);
        *(float4*)(&tile[k][nc4]) = f;
    }
    __syncthreads();
    const int n = tid >> 2;           // 0..63
    const int kc = (tid & 3) * 16;    // 0,16,32,48
    u16 buf[16];
#pragma unroll
    for (int j = 0; j < 16; ++j) buf[j] = f2bf(tile[kc + j][n]);
    u16* op = outp + (size_t)(n0 + n) * K + k0 + kc;
    *(uint4*)(op)     = *(uint4*)&buf[0];
    *(uint4*)(op + 8) = *(uint4*)&buf[8];
}

// ---------------- router (fused x->bf16 cast, block-level atomics) ----------------
__global__ __launch_bounds__(256) void router_kernel(const float* __restrict__ x,
                                                     const float* __restrict__ rw,
                                                     const float* __restrict__ rb,
                                                     u16* __restrict__ xb,
                                                     int* __restrict__ tok_expert,
                                                     float* __restrict__ tok_w,
                                                     int* __restrict__ ctrl,
                                                     float* __restrict__ aux) {
    __shared__ int hist[NE];
    __shared__ float auxsh;
    const int tid = threadIdx.x;
    if (tid < NE) hist[tid] = 0;
    if (tid == NE) auxsh = 0.f;
    __syncthreads();

    const int wave = tid >> 6, lane = tid & 63;
    const int t = blockIdx.x * 4 + wave;
    const float* xr = x + (size_t)t * DIM;
    u16* xbr = xb + (size_t)t * DIM;

    float p[NE];
#pragma unroll
    for (int e = 0; e < NE; e++) p[e] = 0.f;
#pragma unroll
    for (int q = 0; q < 4; ++q) {
        const int d = q * 256 + lane * 4;
        float4 f = *(const float4*)(xr + d);
        uint2 v;
        v.x = (unsigned)f2bf(f.x) | ((unsigned)f2bf(f.y) << 16);
        v.y = (unsigned)f2bf(f.z) | ((unsigned)f2bf(f.w) << 16);
        *(uint2*)(xbr + d) = v;
#pragma unroll
        for (int e = 0; e < NE; e++) {
            float4 w = *(const float4*)(rw + e * DIM + d);
            p[e] += f.x * w.x + f.y * w.y + f.z * w.z + f.w * w.w;
        }
    }
#pragma unroll
    for (int e = 0; e < NE; e++) {
#pragma unroll
        for (int off = 32; off; off >>= 1) p[e] += __shfl_down(p[e], off, 64);
    }
    if (lane == 0) {
        float s[NE]; float auxs = 0.f;
#pragma unroll
        for (int e = 0; e < NE; e++) {
            float lg = p[e] + rb[e];
            auxs += lg * lg;
            s[e] = 1.f / (1.f + __expf(-lg));
        }
        atomicAdd(&auxsh, auxs);
        unsigned mask = 0; float wsum = 0.f;
        int idxs[TOPK]; float vals[TOPK];
        for (int k = 0; k < TOPK; k++) {
            float best = -1.f; int bi = 0;
            for (int e = 0; e < NE; e++)
                if (!((mask >> e) & 1u) && s[e] > best) { best = s[e]; bi = e; }
            mask |= 1u << bi; idxs[k] = bi; vals[k] = best; wsum += best;
        }
        wsum += 1e-6f;
        for (int k = 0; k < TOPK; k++) {
            tok_expert[t * TOPK + k] = idxs[k];
            tok_w[t * TOPK + k] = vals[k] / wsum;
            atomicAdd(&hist[idxs[k]], 1);
        }
    }
    __syncthreads();
    if (tid < NE) { int h = hist[tid]; if (h) atomicAdd(&ctrl[tid], h); }
    if (tid == NE) atomicAdd(aux, auxsh * (0.01f / 32768.0f));
}

// assign: two-level atomics — per-block LDS histogram, one global reservation
// per expert per block (8 global atomics vs 768). Slot order within an expert is
// a permutation; all consumers are permutation-invariant.
__global__ __launch_bounds__(256) void assign_kernel(const int* __restrict__ tok_expert,
                                                     int* __restrict__ ctrl,
                                                     int* __restrict__ pair_token,
                                                     int* __restrict__ tok_slot) {
    __shared__ int soff[NE];   // global expert start (prefix of counts)
    __shared__ int hist[NE];   // this block's per-expert count
    __shared__ int base[NE];   // this block's reserved base within expert
    const int tid = threadIdx.x;
    if (tid < NE) {
        int acc = 0;
        for (int i = 0; i < tid; ++i) acc += ctrl[i];
        soff[tid] = acc;
        hist[tid] = 0;
    }
    __syncthreads();
    const int t = blockIdx.x * blockDim.x + tid;
    int e[TOPK], p[TOPK];
#pragma unroll
    for (int k = 0; k < TOPK; k++) {
        e[k] = tok_expert[t * TOPK + k];
        p[k] = atomicAdd(&hist[e[k]], 1);
    }
    __syncthreads();
    if (tid < NE && hist[tid]) base[tid] = atomicAdd(&ctrl[16 + tid], hist[tid]);
    __syncthreads();
#pragma unroll
    for (int k = 0; k < TOPK; k++) {
        const int slot = soff[e[k]] + base[e[k]] + p[k];
        pair_token[slot] = t;
        tok_slot[t * TOPK + k] = slot;
    }
}

// ---------------- GEMM1: hidden = silu(x@w1)*(x@w2), gathered rows ----------------
// Round-2 schedule verbatim (best measured 239 us / MfmaUtil 41%): quarter staging,
// counted vmcnt 4/6/6, one barrier per phase, lgkm wall before each MFMA cluster.
__global__ __launch_bounds__(512, 2) void gemm1_kernel(const u16* __restrict__ xb,
                                                       const u16* __restrict__ w12t,
                                                       const int* __restrict__ pair_token,
                                                       const int* __restrict__ ctrl,
                                                       u16* __restrict__ hidden) {
    const int e = blockIdx.z;
    const int cnt = ctrl[e];
    if ((int)blockIdx.y * 256 >= cnt) return;
    int off = 0;
    for (int i = 0; i < e; ++i) off += ctrl[i];
    const int rowbase = off + blockIdx.y * 256;
    const int rowend = off + cnt;
    const int n0 = blockIdx.x * 128;   // col base within each half

    extern __shared__ __align__(16) u16 lds[];   // 2 slots x 32768 u16

    const int tid = threadIdx.x;
    const int wave = tid >> 6, lane = tid & 63;
    const int srow = tid >> 3;                       // 0..63 row-in-round
    const int scol = ((tid & 7) ^ (srow & 7)) * 8;   // pre-swizzled global col

    const u16* srcA[4];
    const u16* srcB[4];
#pragma unroll
    for (int r = 0; r < 4; ++r) {
        int sr = rowbase + r * 64 + srow;
        int tok = (sr < rowend) ? pair_token[sr] : 0;
        srcA[r] = xb + (size_t)tok * DIM + scol;
    }
#pragma unroll
    for (int r = 0; r < 2; ++r) {
        srcB[r]     = w12t + ((size_t)e * 2 * HID + n0 + r * 64 + srow) * DIM + scol; // w1
        srcB[r + 2] = srcB[r] + (size_t)HID * DIM;                                    // w2
    }

    const int wm = wave >> 2, wn = wave & 3;
    const int lrow = lane & 15, lq = lane >> 4, xm = lrow & 7;
    const int so0 = ((lq ^ xm) << 3);
    const int so1 = (((4 | lq) ^ xm) << 3);

    f32x4 acc0[8][2], acc1[8][2];
#pragma unroll
    for (int mf = 0; mf < 8; ++mf)
#pragma unroll
        for (int nf = 0; nf < 2; ++nf) { acc0[mf][nf] = (f32x4)0.f; acc1[mf][nf] = (f32x4)0.f; }

    // prologue: stage K-tile 0 in queue order [p0-set(4), p1-set(2), p2-set(2)]
    STAGE_A02(lds); STAGE_B01(lds);
    STAGE_B23(lds);
    STAGE_A13(lds);
    ADV();

    const int NT = DIM / 64;   // 16
    for (int kt = 0; kt < NT; ++kt) {
        u16* cur = lds + (kt & 1) * 32768;
        u16* nxt = lds + ((kt & 1) ^ 1) * 32768;
        const u16* sA = cur;
        const u16* sB = cur + 16384;
        const bool notlast = (kt < NT - 1);

        bf16x8 a[4][2], b0[2][2], b1[2][2];
        // ---- phase 0: wait p0-set; read A-lo + B0; issue next p0-set ----
        VMCNT(4); SBAR; SCHED0;
#pragma unroll
        for (int mf = 0; mf < 4; ++mf) {
            const u16* base = sA + (wm * 128 + mf * 16 + lrow) * 64;
            a[mf][0] = *(const bf16x8*)(base + so0);
            a[mf][1] = *(const bf16x8*)(base + so1);
        }
#pragma unroll
        for (int nf = 0; nf < 2; ++nf) {
            const u16* base = sB + (wn * 32 + nf * 16 + lrow) * 64;
            b0[nf][0] = *(const bf16x8*)(base + so0);
            b0[nf][1] = *(const bf16x8*)(base + so1);
        }
        if (notlast) { STAGE_A02(nxt); STAGE_B01(nxt); }
        LGKM0; SCHED0;
        PRIO1;
#pragma unroll
        for (int mf = 0; mf < 4; ++mf)
#pragma unroll
            for (int nf = 0; nf < 2; ++nf) {
                acc0[mf][nf] = __builtin_amdgcn_mfma_f32_16x16x32_bf16(a[mf][0], b0[nf][0], acc0[mf][nf], 0, 0, 0);
                acc0[mf][nf] = __builtin_amdgcn_mfma_f32_16x16x32_bf16(a[mf][1], b0[nf][1], acc0[mf][nf], 0, 0, 0);
            }
        PRIO0;
        // ---- phase 1: wait p1-set; read B1; issue next p1-set ----
        if (notlast) { VMCNT(6); } else { VMCNT(2); }
        SBAR; SCHED0;
#pragma unroll
        for (int nf = 0; nf < 2; ++nf) {
            const u16* base = sB + 128 * 64 + (wn * 32 + nf * 16 + lrow) * 64;
            b1[nf][0] = *(const bf16x8*)(base + so0);
            b1[nf][1] = *(const bf16x8*)(base + so1);
        }
        if (notlast) STAGE_B23(nxt);
        LGKM0; SCHED0;
        PRIO1;
#pragma unroll
        for (int mf = 0; mf < 4; ++mf)
#pragma unroll
            for (int nf = 0; nf < 2; ++nf) {
                acc1[mf][nf] = __builtin_amdgcn_mfma_f32_16x16x32_bf16(a[mf][0], b1[nf][0], acc1[mf][nf], 0, 0, 0);
                acc1[mf][nf] = __builtin_amdgcn_mfma_f32_16x16x32_bf16(a[mf][1], b1[nf][1], acc1[mf][nf], 0, 0, 0);
            }
        PRIO0;
        // ---- phase 2: wait p2-set; read A-hi; issue next p2-set ----
        if (notlast) { VMCNT(6); } else { VMCNT(0); }
        SBAR; SCHED0;
#pragma unroll
        for (int mf = 0; mf < 4; ++mf) {
            const u16* base = sA + (wm * 128 + (mf + 4) * 16 + lrow) * 64;
            a[mf][0] = *(const bf16x8*)(base + so0);
            a[mf][1] = *(const bf16x8*)(base + so1);
        }
        if (notlast) { STAGE_A13(nxt); ADV(); }
        LGKM0; SCHED0;
        PRIO1;
#pragma unroll
        for (int mf = 0; mf < 4; ++mf)
#pragma unroll
            for (int nf = 0; nf < 2; ++nf) {
                acc1[mf + 4][nf] = __builtin_amdgcn_mfma_f32_16x16x32_bf16(a[mf][0], b1[nf][0], acc1[mf + 4][nf], 0, 0, 0);
                acc1[mf + 4][nf] = __builtin_amdgcn_mfma_f32_16x16x32_bf16(a[mf][1], b1[nf][1], acc1[mf + 4][nf], 0, 0, 0);
            }
        PRIO0;
        // ---- phase 3: no reads, no waits (reuse A-hi + B0) ----
        SBAR;
        PRIO1;
#pragma unroll
        for (int mf = 0; mf < 4; ++mf)
#pragma unroll
            for (int nf = 0; nf < 2; ++nf) {
                acc0[mf + 4][nf] = __builtin_amdgcn_mfma_f32_16x16x32_bf16(a[mf][0], b0[nf][0], acc0[mf + 4][nf], 0, 0, 0);
                acc0[mf + 4][nf] = __builtin_amdgcn_mfma_f32_16x16x32_bf16(a[mf][1], b0[nf][1], acc0[mf + 4][nf], 0, 0, 0);
            }
        PRIO0;
    }

#pragma unroll
    for (int mf = 0; mf < 8; ++mf) {
        const int gr0 = rowbase + wm * 128 + mf * 16 + lq * 4;
#pragma unroll
        for (int nf = 0; nf < 2; ++nf) {
            const int gc = n0 + wn * 32 + nf * 16 + lrow;
#pragma unroll
            for (int r = 0; r < 4; ++r) {
                const int gr = gr0 + r;
                if (gr < rowend) {
                    float x1 = acc0[mf][nf][r], x2 = acc1[mf][nf][r];
                    float h = x1 / (1.f + __expf(-x1)) * x2;
                    hidden[(size_t)gr * HID + gc] = f2bf(h);
                }
            }
        }
    }
}

// ---------------- GEMM2: y = hidden @ w3 ----------------
// Round-4 variant (no lgkm walls): 256x256 tile, BK=64, 8 waves, counted vmcnt.
__global__ __launch_bounds__(512, 2) void gemm2_kernel(const u16* __restrict__ hidden,
                                                       const u16* __restrict__ w3t,
                                                       const int* __restrict__ ctrl,
                                                       float* __restrict__ ybuf) {
    const int e = blockIdx.z;
    const int cnt = ctrl[e];
    if ((int)blockIdx.y * 256 >= cnt) return;
    int off = 0;
    for (int i = 0; i < e; ++i) off += ctrl[i];
    const int rowbase = off + blockIdx.y * 256;
    const int rowend = off + cnt;
    const int n0 = blockIdx.x * 256;

    extern __shared__ __align__(16) u16 lds[];

    const int tid = threadIdx.x;
    const int wave = tid >> 6, lane = tid & 63;
    const int srow = tid >> 3;
    const int scol = ((tid & 7) ^ (srow & 7)) * 8;

    const u16* srcA[4];
    const u16* srcB[4];
#pragma unroll
    for (int r = 0; r < 4; ++r) {
        int sr = rowbase + r * 64 + srow;
        if (sr > NPAIR - 1) sr = NPAIR - 1;
        srcA[r] = hidden + (size_t)sr * HID + scol;
        srcB[r] = w3t + ((size_t)e * DIM + n0 + r * 64 + srow) * HID + scol;
    }

    const int wm = wave >> 2, wn = wave & 3;
    const int lrow = lane & 15, lq = lane >> 4, xm = lrow & 7;
    const int so0 = ((lq ^ xm) << 3);
    const int so1 = (((4 | lq) ^ xm) << 3);

    f32x4 acc[8][4];
#pragma unroll
    for (int mf = 0; mf < 8; ++mf)
#pragma unroll
        for (int nf = 0; nf < 4; ++nf) acc[mf][nf] = (f32x4)0.f;

    STAGE_A02(lds); STAGE_B01(lds);
    STAGE_B23(lds);
    STAGE_A13(lds);
    ADV();

    const int NT = HID / 64;   // 64
    for (int kt = 0; kt < NT; ++kt) {
        u16* cur = lds + (kt & 1) * 32768;
        u16* nxt = lds + ((kt & 1) ^ 1) * 32768;
        const u16* sA = cur;
        const u16* sB = cur + 16384;
        const bool notlast = (kt < NT - 1);

        bf16x8 a[4][2], b[4][2];
        // ---- phase 0: wait p0-set; read A-lo + B[0..1]; issue next p0-set; MFMA ----
        VMCNT(4); SBAR;
#pragma unroll
        for (int mf = 0; mf < 4; ++mf) {
            const u16* base = sA + (wm * 128 + mf * 16 + lrow) * 64;
            a[mf][0] = *(const bf16x8*)(base + so0);
            a[mf][1] = *(const bf16x8*)(base + so1);
        }
#pragma unroll
        for (int nf = 0; nf < 2; ++nf) {
            const u16* base = sB + (nf * 64 + wn * 16 + lrow) * 64;
            b[nf][0] = *(const bf16x8*)(base + so0);
            b[nf][1] = *(const bf16x8*)(base + so1);
        }
        if (notlast) { STAGE_A02(nxt); STAGE_B01(nxt); }
        PRIO1;
#pragma unroll
        for (int mf = 0; mf < 4; ++mf)
#pragma unroll
            for (int nf = 0; nf < 2; ++nf) {
                acc[mf][nf] = __builtin_amdgcn_mfma_f32_16x16x32_bf16(a[mf][0], b[nf][0], acc[mf][nf], 0, 0, 0);
                acc[mf][nf] = __builtin_amdgcn_mfma_f32_16x16x32_bf16(a[mf][1], b[nf][1], acc[mf][nf], 0, 0, 0);
            }
        PRIO0;
        // ---- phase 1: wait p1-set; read B[2..3]; issue next p1-set; MFMA ----
        if (notlast) { VMCNT(6); } else { VMCNT(2); }
        SBAR;
#pragma unroll
        for (int nf = 2; nf < 4; ++nf) {
            const u16* base = sB + (nf * 64 + wn * 16 + lrow) * 64;
            b[nf][0] = *(const bf16x8*)(base + so0);
            b[nf][1] = *(const bf16x8*)(base + so1);
        }
        if (notlast) STAGE_B23(nxt);
        PRIO1;
#pragma unroll
        for (int mf = 0; mf < 4; ++mf)
#pragma unroll
            for (int nf = 2; nf < 4; ++nf) {
                acc[mf][nf] = __builtin_amdgcn_mfma_f32_16x16x32_bf16(a[mf][0], b[nf][0], acc[mf][nf], 0, 0, 0);
                acc[mf][nf] = __builtin_amdgcn_mfma_f32_16x16x32_bf16(a[mf][1], b[nf][1], acc[mf][nf], 0, 0, 0);
            }
        PRIO0;
        // ---- phase 2: wait p2-set; read A-hi; issue next p2-set; MFMA ----
        if (notlast) { VMCNT(6); } else { VMCNT(0); }
        SBAR;
#pragma unroll
        for (int mf = 0; mf < 4; ++mf) {
            const u16* base = sA + (wm * 128 + (mf + 4) * 16 + lrow) * 64;
            a[mf][0] = *(const bf16x8*)(base + so0);
            a[mf][1] = *(const bf16x8*)(base + so1);
        }
        if (notlast) { STAGE_A13(nxt); ADV(); }
        PRIO1;
#pragma unroll
        for (int mf = 0; mf < 4; ++mf)
#pragma unroll
            for (int nf = 2; nf < 4; ++nf) {
                acc[mf + 4][nf] = __builtin_amdgcn_mfma_f32_16x16x32_bf16(a[mf][0], b[nf][0], acc[mf + 4][nf], 0, 0, 0);
                acc[mf + 4][nf] = __builtin_amdgcn_mfma_f32_16x16x32_bf16(a[mf][1], b[nf][1], acc[mf + 4][nf], 0, 0, 0);
            }
        PRIO0;
        // ---- phase 3: no reads, no waits (A-hi + B[0..1]) ----
        SBAR;
        PRIO1;
#pragma unroll
        for (int mf = 0; mf < 4; ++mf)
#pragma unroll
            for (int nf = 0; nf < 2; ++nf) {
                acc[mf + 4][nf] = __builtin_amdgcn_mfma_f32_16x16x32_bf16(a[mf][0], b[nf][0], acc[mf + 4][nf], 0, 0, 0);
                acc[mf + 4][nf] = __builtin_amdgcn_mfma_f32_16x16x32_bf16(a[mf][1], b[nf][1], acc[mf + 4][nf], 0, 0, 0);
            }
        PRIO0;
    }

#pragma unroll
    for (int mf = 0; mf < 8; ++mf) {
        const int gr0 = rowbase + wm * 128 + mf * 16 + lq * 4;
#pragma unroll
        for (int nf = 0; nf < 4; ++nf) {
            const int gc = n0 + nf * 64 + wn * 16 + lrow;
#pragma unroll
            for (int r = 0; r < 4; ++r) {
                const int gr = gr0 + r;
                if (gr < rowend) ybuf[(size_t)gr * DIM + gc] = acc[mf][nf][r];
            }
        }
    }
}

// ---------------- combine: out[t] = sum_k w_k * y[slot_k] ----------------
__global__ __launch_bounds__(256) void combine_kernel(const float* __restrict__ ybuf,
                                                      const int* __restrict__ tok_slot,
                                                      const float* __restrict__ tok_w,
                                                      float* __restrict__ out) {
    const int t = blockIdx.x;
    const int d = threadIdx.x * 4;
    const int s0 = tok_slot[t * 3 + 0], s1 = tok_slot[t * 3 + 1], s2 = tok_slot[t * 3 + 2];
    const float w0 = tok_w[t * 3 + 0], w1 = tok_w[t * 3 + 1], w2 = tok_w[t * 3 + 2];
    const float4 a0 = *(const float4*)(ybuf + (size_t)s0 * DIM + d);
    const float4 a1 = *(const float4*)(ybuf + (size_t)s1 * DIM + d);
    const float4 a2 = *(const float4*)(ybuf + (size_t)s2 * DIM + d);
    float4 o;
    o.x = w0 * a0.x + w1 * a1.x + w2 * a2.x;
    o.y = w0 * a0.y + w1 * a1.y + w2 * a2.y;
    o.z = w0 * a0.z + w1 * a1.z + w2 * a2.z;
    o.w = w0 * a0.w + w1 * a1.w + w2 * a2.w;
    *(float4*)(out + (size_t)t * DIM + d) = o;
}

extern "C" void kernel_launch(void* const* d_in, const int* in_sizes, int n_in,
                              void* d_out, int out_size, void* d_ws, size_t ws_size,
                              hipStream_t stream) {
    const float* x   = (const float*)d_in[0];
    const float* rw  = (const float*)d_in[1];
    const float* rb  = (const float*)d_in[2];
    const float* w12 = (const float*)d_in[3];
    const float* w3  = (const float*)d_in[4];
    float* out = (float*)d_out;
    char* ws = (char*)d_ws;

    int*   ctrl       = (int*)(ws + OFF_CTRL);
    u16*   xb         = (u16*)(ws + OFF_XB);
    u16*   w12t       = (u16*)(ws + OFF_W12T);
    u16*   w3t        = (u16*)(ws + OFF_W3T);
    u16*   hidden     = (u16*)(ws + OFF_HID);
    float* ybuf       = (float*)(ws + OFF_Y);
    int*   pair_token = (int*)(ws + OFF_PTOK);
    int*   tok_expert = (int*)(ws + OFF_TE);
    float* tok_w      = (float*)(ws + OFF_TW);
    int*   tok_slot   = (int*)(ws + OFF_TS);

    static bool attr_set = false;
    if (!attr_set) {
        hipFuncSetAttribute((const void*)gemm1_kernel, hipFuncAttributeMaxDynamicSharedMemorySize, 131072);
        hipFuncSetAttribute((const void*)gemm2_kernel, hipFuncAttributeMaxDynamicSharedMemorySize, 131072);
        attr_set = true;
    }

    hipMemsetAsync(ctrl, 0, 256, stream);
    hipMemsetAsync(out + (size_t)T_TOK * DIM, 0, sizeof(float), stream);  // aux slot

    router_kernel<<<T_TOK / 4, 256, 0, stream>>>(x, rw, rb, xb, tok_expert, tok_w, ctrl,
                                                 out + (size_t)T_TOK * DIM);
    transpose_cast_kernel<<<dim3(2 * HID / 64, DIM / 64, NE), 256, 0, stream>>>(w12, w12t, DIM, 2 * HID);
    transpose_cast_kernel<<<dim3(DIM / 64, HID / 64, NE), 256, 0, stream>>>(w3, w3t, HID, DIM);
    assign_kernel<<<16, 256, 0, stream>>>(tok_expert, ctrl, pair_token, tok_slot);

    gemm1_kernel<<<dim3(HID / 128, 16, NE), 512, 131072, stream>>>(xb, w12t, pair_token, ctrl, hidden);
    gemm2_kernel<<<dim3(DIM / 256, 16, NE), 512, 131072, stream>>>(hidden, w3t, ctrl, ybuf);
    combine_kernel<<<T_TOK, 256, 0, stream>>>(ybuf, tok_slot, tok_w, out);
    (void)in_sizes; (void)n_in; (void)out_size; (void)ws_size;
}

// Round 6
// 805.040 us; speedup vs baseline: 1.1262x; 1.0206x over previous
//
#include <hip/hip_runtime.h>
#include <math.h>

typedef unsigned short u16;
typedef __bf16 bf16x8 __attribute__((ext_vector_type(8)));
typedef float f32x4 __attribute__((ext_vector_type(4)));

#define T_TOK 4096
#define DIM   1024
#define HID   4096
#define NE    8
#define TOPK  3
#define NPAIR 12288   // T_TOK * TOPK

// ---------------- ws layout (bytes) ----------------
// ctrl ints: [0..7]=ecnt, [16..23]=efill
constexpr size_t OFF_CTRL = 0;
constexpr size_t OFF_XB   = 256;
constexpr size_t OFF_W12T = OFF_XB   + (size_t)T_TOK * DIM * 2;
constexpr size_t OFF_W3T  = OFF_W12T + (size_t)NE * 2 * HID * DIM * 2;
constexpr size_t OFF_HID  = OFF_W3T  + (size_t)NE * DIM * HID * 2;
constexpr size_t OFF_Y    = OFF_HID  + (size_t)NPAIR * HID * 2;
constexpr size_t OFF_PTOK = OFF_Y    + (size_t)NPAIR * DIM * 4;
constexpr size_t OFF_TE   = OFF_PTOK + (size_t)NPAIR * 4;
constexpr size_t OFF_TW   = OFF_TE   + (size_t)T_TOK * TOPK * 4;
constexpr size_t OFF_TS   = OFF_TW   + (size_t)T_TOK * TOPK * 4;

__device__ __forceinline__ u16 f2bf(float f) {
    unsigned u = __builtin_bit_cast(unsigned, f);
    u += 0x7fffu + ((u >> 16) & 1u);   // RNE
    return (u16)(u >> 16);
}

// async global->LDS DMA, 16B per lane; LDS dst = wave-uniform base + lane*16
__device__ __forceinline__ void ld_g2l(const u16* g, u16* l) {
    __builtin_amdgcn_global_load_lds((__attribute__((address_space(1))) unsigned*)(g),
                                     (__attribute__((address_space(3))) unsigned*)(l),
                                     16, 0, 0);
}

// raw sync primitives: raw s_barrier does NOT drain vmcnt (that's the point)
#define VMCNT(N) asm volatile("s_waitcnt vmcnt(" #N ")" ::: "memory")
#define LGKM0  asm volatile("s_waitcnt lgkmcnt(0)" ::: "memory")
#define SBAR   __builtin_amdgcn_s_barrier()
#define SCHED0 __builtin_amdgcn_sched_barrier(0)
#define PRIO1  __builtin_amdgcn_s_setprio(1)
#define PRIO0  __builtin_amdgcn_s_setprio(0)

// quarter staging macros (2 global_load_lds each)
#define STAGE_A02(dst) { ld_g2l(srcA[0], (dst) + (0 * 64 + wave * 8) * 64); \
                         ld_g2l(srcA[2], (dst) + (2 * 64 + wave * 8) * 64); }
#define STAGE_B01(dst) { ld_g2l(srcB[0], (dst) + 16384 + (0 * 64 + wave * 8) * 64); \
                         ld_g2l(srcB[1], (dst) + 16384 + (1 * 64 + wave * 8) * 64); }
#define STAGE_B23(dst) { ld_g2l(srcB[2], (dst) + 16384 + (2 * 64 + wave * 8) * 64); \
                         ld_g2l(srcB[3], (dst) + 16384 + (3 * 64 + wave * 8) * 64); }
#define STAGE_A13(dst) { ld_g2l(srcA[1], (dst) + (1 * 64 + wave * 8) * 64); \
                         ld_g2l(srcA[3], (dst) + (3 * 64 + wave * 8) * 64); }
#define ADV()          { _Pragma("unroll") \
                         for (int r_ = 0; r_ < 4; ++r_) { srcA[r_] += 64; srcB[r_] += 64; } }

// 64x64 transpose-cast tile body (K,N compile-time at each call site)
__device__ __forceinline__ void tc_tile(const float* __restrict__ inp, u16* __restrict__ outp,
                                        int K, int N, int n0, int k0, int tid,
                                        float (*tile)[68]) {
    const int kr = tid >> 4;          // 0..15
    const int nc4 = (tid & 15) * 4;   // 0,4,..,60
#pragma unroll
    for (int i = 0; i < 4; ++i) {
        const int k = i * 16 + kr;
        float4 f = *(const float4*)(inp + (size_t)(k0 + k) * N + n0 + nc4);
        *(float4*)(&tile[k][nc4]) = f;
    }
    __syncthreads();
    const int n = tid >> 2;           // 0..63
    const int kc = (tid & 3) * 16;    // 0,16,32,48
    u16 buf[16];
#pragma unroll
    for (int j = 0; j < 16; ++j) buf[j] = f2bf(tile[kc + j][n]);
    u16* op = outp + (size_t)(n0 + n) * K + k0 + kc;
    *(uint4*)(op)     = *(uint4*)&buf[0];
    *(uint4*)(op + 8) = *(uint4*)&buf[8];
}

// ---------------- prep: router + w12 transpose + w3 transpose in ONE launch ----
// Flat grid: [0,1024) router blocks, [1024,9216) w3 tiles, [9216,25600) w12 tiles.
// Router blocks dispatch first (they gate assign); transposes fill the machine.
__global__ __launch_bounds__(256) void prep_kernel(const float* __restrict__ x,
                                                   const float* __restrict__ rw,
                                                   const float* __restrict__ rb,
                                                   u16* __restrict__ xb,
                                                   int* __restrict__ tok_expert,
                                                   float* __restrict__ tok_w,
                                                   int* __restrict__ ctrl,
                                                   float* __restrict__ aux,
                                                   const float* __restrict__ w12,
                                                   u16* __restrict__ w12t,
                                                   const float* __restrict__ w3,
                                                   u16* __restrict__ w3t) {
    __shared__ float tile[64][68];
    const int bid = blockIdx.x;
    const int tid = threadIdx.x;

    if (bid >= 9216) {
        // ---- w12 transpose-cast: [DIM][2H] fp32 -> [2H][DIM] bf16, per expert ----
        const int b = bid - 9216;
        const int z = b >> 11;            // /2048
        const int r = b & 2047;
        const int nx = r & 127, ky = r >> 7;
        tc_tile(w12 + (size_t)z * DIM * 2 * HID, w12t + (size_t)z * DIM * 2 * HID,
                DIM, 2 * HID, nx * 64, ky * 64, tid, tile);
        return;
    }
    if (bid >= 1024) {
        // ---- w3 transpose-cast: [HID][DIM] fp32 -> [DIM][HID] bf16, per expert ----
        const int b = bid - 1024;
        const int z = b >> 10;            // /1024
        const int r = b & 1023;
        const int nx = r & 15, ky = r >> 4;
        tc_tile(w3 + (size_t)z * HID * DIM, w3t + (size_t)z * HID * DIM,
                HID, DIM, nx * 64, ky * 64, tid, tile);
        return;
    }

    // ---- router (fused x->bf16 cast, block-level atomics) ----
    int* hist = (int*)&tile[0][0];
    float* auxsh = (float*)&tile[1][0];
    if (tid < NE) hist[tid] = 0;
    if (tid == NE) auxsh[0] = 0.f;
    __syncthreads();

    const int wave = tid >> 6, lane = tid & 63;
    const int t = bid * 4 + wave;
    const float* xr = x + (size_t)t * DIM;
    u16* xbr = xb + (size_t)t * DIM;

    float p[NE];
#pragma unroll
    for (int e = 0; e < NE; e++) p[e] = 0.f;
#pragma unroll
    for (int q = 0; q < 4; ++q) {
        const int d = q * 256 + lane * 4;
        float4 f = *(const float4*)(xr + d);
        uint2 v;
        v.x = (unsigned)f2bf(f.x) | ((unsigned)f2bf(f.y) << 16);
        v.y = (unsigned)f2bf(f.z) | ((unsigned)f2bf(f.w) << 16);
        *(uint2*)(xbr + d) = v;
#pragma unroll
        for (int e = 0; e < NE; e++) {
            float4 w = *(const float4*)(rw + e * DIM + d);
            p[e] += f.x * w.x + f.y * w.y + f.z * w.z + f.w * w.w;
        }
    }
#pragma unroll
    for (int e = 0; e < NE; e++) {
#pragma unroll
        for (int off = 32; off; off >>= 1) p[e] += __shfl_down(p[e], off, 64);
    }
    if (lane == 0) {
        float s[NE]; float auxs = 0.f;
#pragma unroll
        for (int e = 0; e < NE; e++) {
            float lg = p[e] + rb[e];
            auxs += lg * lg;
            s[e] = 1.f / (1.f + __expf(-lg));
        }
        atomicAdd(auxsh, auxs);
        unsigned mask = 0; float wsum = 0.f;
        int idxs[TOPK]; float vals[TOPK];
        for (int k = 0; k < TOPK; k++) {
            float best = -1.f; int bi = 0;
            for (int e = 0; e < NE; e++)
                if (!((mask >> e) & 1u) && s[e] > best) { best = s[e]; bi = e; }
            mask |= 1u << bi; idxs[k] = bi; vals[k] = best; wsum += best;
        }
        wsum += 1e-6f;
        for (int k = 0; k < TOPK; k++) {
            tok_expert[t * TOPK + k] = idxs[k];
            tok_w[t * TOPK + k] = vals[k] / wsum;
            atomicAdd(&hist[idxs[k]], 1);
        }
    }
    __syncthreads();
    if (tid < NE) { int h = hist[tid]; if (h) atomicAdd(&ctrl[tid], h); }
    if (tid == NE) atomicAdd(aux, auxsh[0] * (0.01f / 32768.0f));
}

// assign: two-level atomics — per-block LDS histogram, one global reservation
// per expert per block. Slot order within an expert is a permutation;
// all consumers are permutation-invariant.
__global__ __launch_bounds__(256) void assign_kernel(const int* __restrict__ tok_expert,
                                                     int* __restrict__ ctrl,
                                                     int* __restrict__ pair_token,
                                                     int* __restrict__ tok_slot) {
    __shared__ int soff[NE];   // global expert start (prefix of counts)
    __shared__ int hist[NE];   // this block's per-expert count
    __shared__ int base[NE];   // this block's reserved base within expert
    const int tid = threadIdx.x;
    if (tid < NE) {
        int acc = 0;
        for (int i = 0; i < tid; ++i) acc += ctrl[i];
        soff[tid] = acc;
        hist[tid] = 0;
    }
    __syncthreads();
    const int t = blockIdx.x * blockDim.x + tid;
    int e[TOPK], p[TOPK];
#pragma unroll
    for (int k = 0; k < TOPK; k++) {
        e[k] = tok_expert[t * TOPK + k];
        p[k] = atomicAdd(&hist[e[k]], 1);
    }
    __syncthreads();
    if (tid < NE && hist[tid]) base[tid] = atomicAdd(&ctrl[16 + tid], hist[tid]);
    __syncthreads();
#pragma unroll
    for (int k = 0; k < TOPK; k++) {
        const int slot = soff[e[k]] + base[e[k]] + p[k];
        pair_token[slot] = t;
        tok_slot[t * TOPK + k] = slot;
    }
}

// ---------------- GEMM1: hidden = silu(x@w1)*(x@w2), gathered rows ----------------
// Round-2 schedule verbatim (best measured 236 us / MfmaUtil 41.5%): quarter staging,
// counted vmcnt 4/6/6, one barrier per phase, lgkm wall before each MFMA cluster.
__global__ __launch_bounds__(512, 2) void gemm1_kernel(const u16* __restrict__ xb,
                                                       const u16* __restrict__ w12t,
                                                       const int* __restrict__ pair_token,
                                                       const int* __restrict__ ctrl,
                                                       u16* __restrict__ hidden) {
    const int e = blockIdx.z;
    const int cnt = ctrl[e];
    if ((int)blockIdx.y * 256 >= cnt) return;
    int off = 0;
    for (int i = 0; i < e; ++i) off += ctrl[i];
    const int rowbase = off + blockIdx.y * 256;
    const int rowend = off + cnt;
    const int n0 = blockIdx.x * 128;   // col base within each half

    extern __shared__ __align__(16) u16 lds[];   // 2 slots x 32768 u16

    const int tid = threadIdx.x;
    const int wave = tid >> 6, lane = tid & 63;
    const int srow = tid >> 3;                       // 0..63 row-in-round
    const int scol = ((tid & 7) ^ (srow & 7)) * 8;   // pre-swizzled global col

    const u16* srcA[4];
    const u16* srcB[4];
#pragma unroll
    for (int r = 0; r < 4; ++r) {
        int sr = rowbase + r * 64 + srow;
        int tok = (sr < rowend) ? pair_token[sr] : 0;
        srcA[r] = xb + (size_t)tok * DIM + scol;
    }
#pragma unroll
    for (int r = 0; r < 2; ++r) {
        srcB[r]     = w12t + ((size_t)e * 2 * HID + n0 + r * 64 + srow) * DIM + scol; // w1
        srcB[r + 2] = srcB[r] + (size_t)HID * DIM;                                    // w2
    }

    const int wm = wave >> 2, wn = wave & 3;
    const int lrow = lane & 15, lq = lane >> 4, xm = lrow & 7;
    const int so0 = ((lq ^ xm) << 3);
    const int so1 = (((4 | lq) ^ xm) << 3);

    f32x4 acc0[8][2], acc1[8][2];
#pragma unroll
    for (int mf = 0; mf < 8; ++mf)
#pragma unroll
        for (int nf = 0; nf < 2; ++nf) { acc0[mf][nf] = (f32x4)0.f; acc1[mf][nf] = (f32x4)0.f; }

    // prologue: stage K-tile 0 in queue order [p0-set(4), p1-set(2), p2-set(2)]
    STAGE_A02(lds); STAGE_B01(lds);
    STAGE_B23(lds);
    STAGE_A13(lds);
    ADV();

    const int NT = DIM / 64;   // 16
    for (int kt = 0; kt < NT; ++kt) {
        u16* cur = lds + (kt & 1) * 32768;
        u16* nxt = lds + ((kt & 1) ^ 1) * 32768;
        const u16* sA = cur;
        const u16* sB = cur + 16384;
        const bool notlast = (kt < NT - 1);

        bf16x8 a[4][2], b0[2][2], b1[2][2];
        // ---- phase 0: wait p0-set; read A-lo + B0; issue next p0-set ----
        VMCNT(4); SBAR; SCHED0;
#pragma unroll
        for (int mf = 0; mf < 4; ++mf) {
            const u16* base = sA + (wm * 128 + mf * 16 + lrow) * 64;
            a[mf][0] = *(const bf16x8*)(base + so0);
            a[mf][1] = *(const bf16x8*)(base + so1);
        }
#pragma unroll
        for (int nf = 0; nf < 2; ++nf) {
            const u16* base = sB + (wn * 32 + nf * 16 + lrow) * 64;
            b0[nf][0] = *(const bf16x8*)(base + so0);
            b0[nf][1] = *(const bf16x8*)(base + so1);
        }
        if (notlast) { STAGE_A02(nxt); STAGE_B01(nxt); }
        LGKM0; SCHED0;
        PRIO1;
#pragma unroll
        for (int mf = 0; mf < 4; ++mf)
#pragma unroll
            for (int nf = 0; nf < 2; ++nf) {
                acc0[mf][nf] = __builtin_amdgcn_mfma_f32_16x16x32_bf16(a[mf][0], b0[nf][0], acc0[mf][nf], 0, 0, 0);
                acc0[mf][nf] = __builtin_amdgcn_mfma_f32_16x16x32_bf16(a[mf][1], b0[nf][1], acc0[mf][nf], 0, 0, 0);
            }
        PRIO0;
        // ---- phase 1: wait p1-set; read B1; issue next p1-set ----
        if (notlast) { VMCNT(6); } else { VMCNT(2); }
        SBAR; SCHED0;
#pragma unroll
        for (int nf = 0; nf < 2; ++nf) {
            const u16* base = sB + 128 * 64 + (wn * 32 + nf * 16 + lrow) * 64;
            b1[nf][0] = *(const bf16x8*)(base + so0);
            b1[nf][1] = *(const bf16x8*)(base + so1);
        }
        if (notlast) STAGE_B23(nxt);
        LGKM0; SCHED0;
        PRIO1;
#pragma unroll
        for (int mf = 0; mf < 4; ++mf)
#pragma unroll
            for (int nf = 0; nf < 2; ++nf) {
                acc1[mf][nf] = __builtin_amdgcn_mfma_f32_16x16x32_bf16(a[mf][0], b1[nf][0], acc1[mf][nf], 0, 0, 0);
                acc1[mf][nf] = __builtin_amdgcn_mfma_f32_16x16x32_bf16(a[mf][1], b1[nf][1], acc1[mf][nf], 0, 0, 0);
            }
        PRIO0;
        // ---- phase 2: wait p2-set; read A-hi; issue next p2-set ----
        if (notlast) { VMCNT(6); } else { VMCNT(0); }
        SBAR; SCHED0;
#pragma unroll
        for (int mf = 0; mf < 4; ++mf) {
            const u16* base = sA + (wm * 128 + (mf + 4) * 16 + lrow) * 64;
            a[mf][0] = *(const bf16x8*)(base + so0);
            a[mf][1] = *(const bf16x8*)(base + so1);
        }
        if (notlast) { STAGE_A13(nxt); ADV(); }
        LGKM0; SCHED0;
        PRIO1;
#pragma unroll
        for (int mf = 0; mf < 4; ++mf)
#pragma unroll
            for (int nf = 0; nf < 2; ++nf) {
                acc1[mf + 4][nf] = __builtin_amdgcn_mfma_f32_16x16x32_bf16(a[mf][0], b1[nf][0], acc1[mf + 4][nf], 0, 0, 0);
                acc1[mf + 4][nf] = __builtin_amdgcn_mfma_f32_16x16x32_bf16(a[mf][1], b1[nf][1], acc1[mf + 4][nf], 0, 0, 0);
            }
        PRIO0;
        // ---- phase 3: no reads, no waits (reuse A-hi + B0) ----
        SBAR;
        PRIO1;
#pragma unroll
        for (int mf = 0; mf < 4; ++mf)
#pragma unroll
            for (int nf = 0; nf < 2; ++nf) {
                acc0[mf + 4][nf] = __builtin_amdgcn_mfma_f32_16x16x32_bf16(a[mf][0], b0[nf][0], acc0[mf + 4][nf], 0, 0, 0);
                acc0[mf + 4][nf] = __builtin_amdgcn_mfma_f32_16x16x32_bf16(a[mf][1], b0[nf][1], acc0[mf + 4][nf], 0, 0, 0);
            }
        PRIO0;
    }

#pragma unroll
    for (int mf = 0; mf < 8; ++mf) {
        const int gr0 = rowbase + wm * 128 + mf * 16 + lq * 4;
#pragma unroll
        for (int nf = 0; nf < 2; ++nf) {
            const int gc = n0 + wn * 32 + nf * 16 + lrow;
#pragma unroll
            for (int r = 0; r < 4; ++r) {
                const int gr = gr0 + r;
                if (gr < rowend) {
                    float x1 = acc0[mf][nf][r], x2 = acc1[mf][nf][r];
                    float h = x1 / (1.f + __expf(-x1)) * x2;
                    hidden[(size_t)gr * HID + gc] = f2bf(h);
                }
            }
        }
    }
}

// ---------------- GEMM2: y = hidden @ w3 ----------------
// 256x256 tile, BK=64, 8 waves (2Mx4N) — round-2 wall schedule (gemm1's best):
// counted vmcnt 4/6/6, lgkm wall + setprio around each MFMA cluster.
__global__ __launch_bounds__(512, 2) void gemm2_kernel(const u16* __restrict__ hidden,
                                                       const u16* __restrict__ w3t,
                                                       const int* __restrict__ ctrl,
                                                       float* __restrict__ ybuf) {
    const int e = blockIdx.z;
    const int cnt = ctrl[e];
    if ((int)blockIdx.y * 256 >= cnt) return;
    int off = 0;
    for (int i = 0; i < e; ++i) off += ctrl[i];
    const int rowbase = off + blockIdx.y * 256;
    const int rowend = off + cnt;
    const int n0 = blockIdx.x * 256;

    extern __shared__ __align__(16) u16 lds[];

    const int tid = threadIdx.x;
    const int wave = tid >> 6, lane = tid & 63;
    const int srow = tid >> 3;
    const int scol = ((tid & 7) ^ (srow & 7)) * 8;

    const u16* srcA[4];
    const u16* srcB[4];
#pragma unroll
    for (int r = 0; r < 4; ++r) {
        int sr = rowbase + r * 64 + srow;
        if (sr > NPAIR - 1) sr = NPAIR - 1;
        srcA[r] = hidden + (size_t)sr * HID + scol;
        srcB[r] = w3t + ((size_t)e * DIM + n0 + r * 64 + srow) * HID + scol;
    }

    const int wm = wave >> 2, wn = wave & 3;
    const int lrow = lane & 15, lq = lane >> 4, xm = lrow & 7;
    const int so0 = ((lq ^ xm) << 3);
    const int so1 = (((4 | lq) ^ xm) << 3);

    f32x4 acc[8][4];
#pragma unroll
    for (int mf = 0; mf < 8; ++mf)
#pragma unroll
        for (int nf = 0; nf < 4; ++nf) acc[mf][nf] = (f32x4)0.f;

    STAGE_A02(lds); STAGE_B01(lds);
    STAGE_B23(lds);
    STAGE_A13(lds);
    ADV();

    const int NT = HID / 64;   // 64
    for (int kt = 0; kt < NT; ++kt) {
        u16* cur = lds + (kt & 1) * 32768;
        u16* nxt = lds + ((kt & 1) ^ 1) * 32768;
        const u16* sA = cur;
        const u16* sB = cur + 16384;
        const bool notlast = (kt < NT - 1);

        bf16x8 a[4][2], b[4][2];
        // ---- phase 0: wait p0-set; read A-lo + B[0..1]; issue next p0-set ----
        VMCNT(4); SBAR; SCHED0;
#pragma unroll
        for (int mf = 0; mf < 4; ++mf) {
            const u16* base = sA + (wm * 128 + mf * 16 + lrow) * 64;
            a[mf][0] = *(const bf16x8*)(base + so0);
            a[mf][1] = *(const bf16x8*)(base + so1);
        }
#pragma unroll
        for (int nf = 0; nf < 2; ++nf) {
            const u16* base = sB + (nf * 64 + wn * 16 + lrow) * 64;
            b[nf][0] = *(const bf16x8*)(base + so0);
            b[nf][1] = *(const bf16x8*)(base + so1);
        }
        if (notlast) { STAGE_A02(nxt); STAGE_B01(nxt); }
        LGKM0; SCHED0;
        PRIO1;
#pragma unroll
        for (int mf = 0; mf < 4; ++mf)
#pragma unroll
            for (int nf = 0; nf < 2; ++nf) {
                acc[mf][nf] = __builtin_amdgcn_mfma_f32_16x16x32_bf16(a[mf][0], b[nf][0], acc[mf][nf], 0, 0, 0);
                acc[mf][nf] = __builtin_amdgcn_mfma_f32_16x16x32_bf16(a[mf][1], b[nf][1], acc[mf][nf], 0, 0, 0);
            }
        PRIO0;
        // ---- phase 1: wait p1-set; read B[2..3]; issue next p1-set ----
        if (notlast) { VMCNT(6); } else { VMCNT(2); }
        SBAR; SCHED0;
#pragma unroll
        for (int nf = 2; nf < 4; ++nf) {
            const u16* base = sB + (nf * 64 + wn * 16 + lrow) * 64;
            b[nf][0] = *(const bf16x8*)(base + so0);
            b[nf][1] = *(const bf16x8*)(base + so1);
        }
        if (notlast) STAGE_B23(nxt);
        LGKM0; SCHED0;
        PRIO1;
#pragma unroll
        for (int mf = 0; mf < 4; ++mf)
#pragma unroll
            for (int nf = 2; nf < 4; ++nf) {
                acc[mf][nf] = __builtin_amdgcn_mfma_f32_16x16x32_bf16(a[mf][0], b[nf][0], acc[mf][nf], 0, 0, 0);
                acc[mf][nf] = __builtin_amdgcn_mfma_f32_16x16x32_bf16(a[mf][1], b[nf][1], acc[mf][nf], 0, 0, 0);
            }
        PRIO0;
        // ---- phase 2: wait p2-set; read A-hi; issue next p2-set ----
        if (notlast) { VMCNT(6); } else { VMCNT(0); }
        SBAR; SCHED0;
#pragma unroll
        for (int mf = 0; mf < 4; ++mf) {
            const u16* base = sA + (wm * 128 + (mf + 4) * 16 + lrow) * 64;
            a[mf][0] = *(const bf16x8*)(base + so0);
            a[mf][1] = *(const bf16x8*)(base + so1);
        }
        if (notlast) { STAGE_A13(nxt); ADV(); }
        LGKM0; SCHED0;
        PRIO1;
#pragma unroll
        for (int mf = 0; mf < 4; ++mf)
#pragma unroll
            for (int nf = 2; nf < 4; ++nf) {
                acc[mf + 4][nf] = __builtin_amdgcn_mfma_f32_16x16x32_bf16(a[mf][0], b[nf][0], acc[mf + 4][nf], 0, 0, 0);
                acc[mf + 4][nf] = __builtin_amdgcn_mfma_f32_16x16x32_bf16(a[mf][1], b[nf][1], acc[mf + 4][nf], 0, 0, 0);
            }
        PRIO0;
        // ---- phase 3: no reads, no waits (A-hi + B[0..1]) ----
        SBAR;
        PRIO1;
#pragma unroll
        for (int mf = 0; mf < 4; ++mf)
#pragma unroll
            for (int nf = 0; nf < 2; ++nf) {
                acc[mf + 4][nf] = __builtin_amdgcn_mfma_f32_16x16x32_bf16(a[mf][0], b[nf][0], acc[mf + 4][nf], 0, 0, 0);
                acc[mf + 4][nf] = __builtin_amdgcn_mfma_f32_16x16x32_bf16(a[mf][1], b[nf][1], acc[mf + 4][nf], 0, 0, 0);
            }
        PRIO0;
    }

#pragma unroll
    for (int mf = 0; mf < 8; ++mf) {
        const int gr0 = rowbase + wm * 128 + mf * 16 + lq * 4;
#pragma unroll
        for (int nf = 0; nf < 4; ++nf) {
            const int gc = n0 + nf * 64 + wn * 16 + lrow;
#pragma unroll
            for (int r = 0; r < 4; ++r) {
                const int gr = gr0 + r;
                if (gr < rowend) ybuf[(size_t)gr * DIM + gc] = acc[mf][nf][r];
            }
        }
    }
}

// ---------------- combine: out[t] = sum_k w_k * y[slot_k] ----------------
__global__ __launch_bounds__(256) void combine_kernel(const float* __restrict__ ybuf,
                                                      const int* __restrict__ tok_slot,
                                                      const float* __restrict__ tok_w,
                                                      float* __restrict__ out) {
    const int t = blockIdx.x;
    const int d = threadIdx.x * 4;
    const int s0 = tok_slot[t * 3 + 0], s1 = tok_slot[t * 3 + 1], s2 = tok_slot[t * 3 + 2];
    const float w0 = tok_w[t * 3 + 0], w1 = tok_w[t * 3 + 1], w2 = tok_w[t * 3 + 2];
    const float4 a0 = *(const float4*)(ybuf + (size_t)s0 * DIM + d);
    const float4 a1 = *(const float4*)(ybuf + (size_t)s1 * DIM + d);
    const float4 a2 = *(const float4*)(ybuf + (size_t)s2 * DIM + d);
    float4 o;
    o.x = w0 * a0.x + w1 * a1.x + w2 * a2.x;
    o.y = w0 * a0.y + w1 * a1.y + w2 * a2.y;
    o.z = w0 * a0.z + w1 * a1.z + w2 * a2.z;
    o.w = w0 * a0.w + w1 * a1.w + w2 * a2.w;
    *(float4*)(out + (size_t)t * DIM + d) = o;
}

extern "C" void kernel_launch(void* const* d_in, const int* in_sizes, int n_in,
                              void* d_out, int out_size, void* d_ws, size_t ws_size,
                              hipStream_t stream) {
    const float* x   = (const float*)d_in[0];
    const float* rw  = (const float*)d_in[1];
    const float* rb  = (const float*)d_in[2];
    const float* w12 = (const float*)d_in[3];
    const float* w3  = (const float*)d_in[4];
    float* out = (float*)d_out;
    char* ws = (char*)d_ws;

    int*   ctrl       = (int*)(ws + OFF_CTRL);
    u16*   xb         = (u16*)(ws + OFF_XB);
    u16*   w12t       = (u16*)(ws + OFF_W12T);
    u16*   w3t        = (u16*)(ws + OFF_W3T);
    u16*   hidden     = (u16*)(ws + OFF_HID);
    float* ybuf       = (float*)(ws + OFF_Y);
    int*   pair_token = (int*)(ws + OFF_PTOK);
    int*   tok_expert = (int*)(ws + OFF_TE);
    float* tok_w      = (float*)(ws + OFF_TW);
    int*   tok_slot   = (int*)(ws + OFF_TS);

    static bool attr_set = false;
    if (!attr_set) {
        hipFuncSetAttribute((const void*)gemm1_kernel, hipFuncAttributeMaxDynamicSharedMemorySize, 131072);
        hipFuncSetAttribute((const void*)gemm2_kernel, hipFuncAttributeMaxDynamicSharedMemorySize, 131072);
        attr_set = true;
    }

    hipMemsetAsync(ctrl, 0, 256, stream);
    hipMemsetAsync(out + (size_t)T_TOK * DIM, 0, sizeof(float), stream);  // aux slot

    // router (blocks 0..1023) + w3 transpose (1024..9215) + w12 transpose (9216..25599)
    prep_kernel<<<25600, 256, 0, stream>>>(x, rw, rb, xb, tok_expert, tok_w, ctrl,
                                           out + (size_t)T_TOK * DIM, w12, w12t, w3, w3t);
    assign_kernel<<<16, 256, 0, stream>>>(tok_expert, ctrl, pair_token, tok_slot);

    gemm1_kernel<<<dim3(HID / 128, 16, NE), 512, 131072, stream>>>(xb, w12t, pair_token, ctrl, hidden);
    gemm2_kernel<<<dim3(DIM / 256, 16, NE), 512, 131072, stream>>>(hidden, w3t, ctrl, ybuf);
    combine_kernel<<<T_TOK, 256, 0, stream>>>(ybuf, tok_slot, tok_w, out);
    (void)in_sizes; (void)n_in; (void)out_size; (void)ws_size;
}